// Round 13
// baseline (1391.632 us; speedup 1.0000x reference)
//
#include <hip/hip_runtime.h>
#include <hip/hip_fp16.h>
#include <math.h>

#define EDGES 120000
#define NN    30000
#define NCH   118   // ceil(30000/256)
#define T1SLOT 15360000   // halfs per slot (NN*64*8)

__device__ __forceinline__ float sigmoidf_(float x) { return 1.f / (1.f + __expf(-x)); }

union F4H8 { float4 v; __half h[8]; };
union F2H4 { float2 v; __half h[4]; };

__device__ __forceinline__ void unpack8(float4 v, float* f) {
  F4H8 u; u.v = v;
#pragma unroll
  for (int i = 0; i < 8; ++i) f[i] = __half2float(u.h[i]);
}
__device__ __forceinline__ float4 pack8(const float* f) {
  F4H8 u;
#pragma unroll
  for (int i = 0; i < 8; ++i) u.h[i] = __float2half(f[i]);
  return u.v;
}
__device__ __forceinline__ void unpack4(float2 v, float* f) {
  F2H4 u; u.v = v;
#pragma unroll
  for (int i = 0; i < 4; ++i) f[i] = __half2float(u.h[i]);
}
__device__ __forceinline__ float2 pack4(const float* f) {
  F2H4 u;
#pragma unroll
  for (int i = 0; i < 4; ++i) u.h[i] = __float2half(f[i]);
  return u.v;
}

// CSR slot layout (ints): rowptr[30016] | pack int2[120000] (src, norm-bits)
#define CSR_STRIDE 270016
#define CSR_RP(base, l)   ((base) + (size_t)(l) * CSR_STRIDE)
#define CSR_PK(base, l)   ((const int2*)((base) + (size_t)(l) * CSR_STRIDE + 30016))
#define CSR_PKW(base, l)  ((int2*)((base) + (size_t)(l) * CSR_STRIDE + 30016))

// ---------------- CSR build ----------------
__global__ void count_all_kernel(const int* __restrict__ hg, const int* __restrict__ tg,
                                 int* __restrict__ degO, int* __restrict__ degI) {
  int tid = blockIdx.x * blockDim.x + threadIdx.x;
  if (tid >= 4 * EDGES) return;
  int l = tid / EDGES, j = tid - l * EDGES;
  const int* G = (l < 2) ? hg : tg;
  const int* src = G + (size_t)(l & 1) * 2 * EDGES;
  const int* dst = src + EDGES;
  atomicAdd(&degO[l * NN + src[j]], 1);
  atomicAdd(&degI[l * NN + dst[j]], 1);
}

__global__ __launch_bounds__(256) void scan1_kernel(const int* __restrict__ degI,
                                                    int* __restrict__ csrBase,
                                                    int* __restrict__ partials) {
  int l = blockIdx.x / NCH, ch = blockIdx.x - l * NCH;
  int tid = threadIdx.x;
  int i = ch * 256 + tid;
  __shared__ int buf[256];
  int v = (i < NN) ? degI[l * NN + i] : 0;
  buf[tid] = v;
  __syncthreads();
  for (int off = 1; off < 256; off <<= 1) {
    int t = (tid >= off) ? buf[tid - off] : 0;
    __syncthreads();
    buf[tid] += t;
    __syncthreads();
  }
  int* rp = CSR_RP(csrBase, l);
  if (i < NN) rp[i + 1] = buf[tid];
  if (tid == 255) partials[l * NCH + ch] = buf[255];
}

__global__ __launch_bounds__(128) void scan2_kernel(int* __restrict__ partials) {
  __shared__ int buf[128];
  int tid = threadIdx.x;
  for (int l = 0; l < 4; ++l) {
    int v = (tid < NCH) ? partials[l * NCH + tid] : 0;
    buf[tid] = v;
    __syncthreads();
    for (int off = 1; off < 128; off <<= 1) {
      int t = (tid >= off) ? buf[tid - off] : 0;
      __syncthreads();
      buf[tid] += t;
      __syncthreads();
    }
    if (tid < NCH) partials[l * NCH + tid] = buf[tid] - v;  // exclusive
    __syncthreads();
  }
}

__global__ __launch_bounds__(256) void fixup_kernel(int* __restrict__ csrBase,
                                                    int* __restrict__ cursor,
                                                    const int* __restrict__ partials) {
  int l = blockIdx.x / NCH, ch = blockIdx.x - l * NCH;
  int i = ch * 256 + threadIdx.x;
  int* rp = CSR_RP(csrBase, l);
  int off = partials[l * NCH + ch];
  if (i < NN) {
    int val = rp[i + 1] + off;
    rp[i + 1] = val;
    if (i + 1 < NN) cursor[l * NN + i + 1] = val;
  }
  if (i == 0) { rp[0] = 0; cursor[l * NN] = 0; }
}

__global__ void fill_all_kernel(const int* __restrict__ hg, const int* __restrict__ tg,
                                const int* __restrict__ degO, const int* __restrict__ degI,
                                int* __restrict__ cursor, int* __restrict__ csrBase) {
  int tid = blockIdx.x * blockDim.x + threadIdx.x;
  if (tid >= 4 * EDGES) return;
  int l = tid / EDGES, j = tid - l * EDGES;
  const int* G = (l < 2) ? hg : tg;
  const int* src = G + (size_t)(l & 1) * 2 * EDGES;
  const int* dst = src + EDGES;
  int s = src[j], d = dst[j];
  int doo = degO[l * NN + s]; if (doo < 1) doo = 1;
  int dii = degI[l * NN + d]; if (dii < 1) dii = 1;
  float nm = rsqrtf((float)doo) * rsqrtf((float)dii);
  int p = atomicAdd(&cursor[l * NN + d], 1);
  CSR_PKW(csrBase, l)[p] = make_int2(s, __float_as_int(nm));
}

// ---------------- block1 temporal GLU conv: x[B,N,6,1] -> X1h [N][64][8] fp16 ----------------
__global__ void glu1_kernel(const float* __restrict__ x, const float* __restrict__ w,
                            const float* __restrict__ b, __half* __restrict__ X1h) {
  int idx = blockIdx.x * blockDim.x + threadIdx.x;   // idx = n*64 + s, s = b*4 + t
  if (idx >= NN * 64) return;
  int n = idx >> 6, s = idx & 63;
  int bb = s >> 2, t = s & 3;
  const float* xb = x + ((long)bb * NN + n) * 6;
  float x0 = xb[t], x1 = xb[t + 1], x2 = xb[t + 2];
  float o[8];
#pragma unroll
  for (int c = 0; c < 8; ++c) {
    float p = w[c * 3 + 0] * x0 + w[c * 3 + 1] * x1 + w[c * 3 + 2] * x2 + b[c];
    float q = w[(c + 8) * 3 + 0] * x0 + w[(c + 8) * 3 + 1] * x1 + w[(c + 8) * 3 + 2] * x2 + b[c + 8];
    float al = (c == 0) ? x2 : 0.f;
    o[c] = (p + al) * sigmoidf_(q);
  }
  reinterpret_cast<float4*>(X1h)[idx] = pack8(o);
}

// ---------------- block1 pull (batched: all 4 lists gather the SHARED X1 buffer) ----------------
__global__ __launch_bounds__(256) void pull1_kernel(const int* __restrict__ csrBase,
                                                    const __half* __restrict__ Xh,
                                                    __half* __restrict__ T1hAll) {
  int gtid = blockIdx.x * 256 + threadIdx.x;
  int l = gtid / (NN * 64);
  int t = gtid - l * (NN * 64);
  int n = t >> 6, j = t & 63;
  const int* rp = CSR_RP(csrBase, l);
  const int2* pk = CSR_PK(csrBase, l);
  const float4* in4 = reinterpret_cast<const float4*>(Xh);
  float acc[8];
#pragma unroll
  for (int i = 0; i < 8; ++i) acc[i] = 0.f;
  int e = rp[n], end = rp[n + 1];
  for (; e + 4 <= end; e += 4) {
    int2 p0 = pk[e], p1 = pk[e + 1], p2 = pk[e + 2], p3 = pk[e + 3];
    float4 v0 = in4[(long)p0.x * 64 + j];
    float4 v1 = in4[(long)p1.x * 64 + j];
    float4 v2 = in4[(long)p2.x * 64 + j];
    float4 v3 = in4[(long)p3.x * 64 + j];
    float f[8];
    float n0 = __int_as_float(p0.y), n1 = __int_as_float(p1.y);
    float n2 = __int_as_float(p2.y), n3 = __int_as_float(p3.y);
    unpack8(v0, f);
#pragma unroll
    for (int i = 0; i < 8; ++i) acc[i] -= n0 * f[i];
    unpack8(v1, f);
#pragma unroll
    for (int i = 0; i < 8; ++i) acc[i] -= n1 * f[i];
    unpack8(v2, f);
#pragma unroll
    for (int i = 0; i < 8; ++i) acc[i] -= n2 * f[i];
    unpack8(v3, f);
#pragma unroll
    for (int i = 0; i < 8; ++i) acc[i] -= n3 * f[i];
  }
  for (; e < end; ++e) {
    int2 p = pk[e];
    float4 v = in4[(long)p.x * 64 + j];
    float nm = __int_as_float(p.y);
    float f[8];
    unpack8(v, f);
#pragma unroll
    for (int i = 0; i < 8; ++i) acc[i] -= nm * f[i];
  }
  reinterpret_cast<float4*>(T1hAll)[(size_t)l * (T1SLOT / 8) + t] = pack8(acc);
}

// ---------------- block1 fused Cheb combine (round-6: both graphs, both etypes) ----------------
__global__ __launch_bounds__(256) void cheb1_kernel(const int* __restrict__ csrBase,
    const __half* __restrict__ Xh, const __half* __restrict__ T1hAll,
    const float* __restrict__ Whg, const float* __restrict__ bhg,
    const float* __restrict__ Wtg, const float* __restrict__ btg,
    __half* __restrict__ outH, __half* __restrict__ outT) {
  constexpr int C = 8, CC = 64;
  __shared__ float wx[CC], w1a[CC], w1b[CC], w2a[CC], w2b[CC], bs[C];
  int gtid = blockIdx.x * 256 + threadIdx.x;
  int g = gtid / (NN * 64);
  int tid = gtid - g * (NN * 64);
  const float* W = g ? Wtg : Whg;
  const float* bias = g ? btg : bhg;
  for (int i = threadIdx.x; i < CC; i += 256) {
    float w0A = W[i], w1A = W[CC + i], w2A = W[2 * CC + i];
    float w0B = W[3 * CC + i], w1B = W[4 * CC + i], w2B = W[5 * CC + i];
    wx[i] = w0A - w2A + w0B - w2B;
    w1a[i] = w1A; w1b[i] = w1B;
    w2a[i] = -2.f * w2A; w2b[i] = -2.f * w2B;
  }
  if (threadIdx.x < C) bs[threadIdx.x] = bias[threadIdx.x] + bias[C + threadIdx.x];
  __syncthreads();
  int n = tid >> 6, s = tid & 63;
  int l0 = 2 * g, l1 = 2 * g + 1;
  const int* rp0 = CSR_RP(csrBase, l0); const int2* pk0 = CSR_PK(csrBase, l0);
  const int* rp1 = CSR_RP(csrBase, l1); const int2* pk1 = CSR_PK(csrBase, l1);
  const float4* A4 = reinterpret_cast<const float4*>(T1hAll + (size_t)l0 * T1SLOT);
  const float4* B4 = reinterpret_cast<const float4*>(T1hAll + (size_t)l1 * T1SLOT);
  float acc0[C], acc1[C];
#pragma unroll
  for (int c = 0; c < C; ++c) { acc0[c] = 0.f; acc1[c] = 0.f; }
  {
    int e = rp0[n], end = rp0[n + 1];
    for (; e + 2 <= end; e += 2) {
      int2 p0 = pk0[e], p1 = pk0[e + 1];
      float4 v0 = A4[(long)p0.x * 64 + s];
      float4 v1 = A4[(long)p1.x * 64 + s];
      float n0 = __int_as_float(p0.y), n1 = __int_as_float(p1.y);
      float f0[8], f1[8];
      unpack8(v0, f0); unpack8(v1, f1);
#pragma unroll
      for (int c = 0; c < C; ++c) acc0[c] += n0 * f0[c] + n1 * f1[c];
    }
    for (; e < end; ++e) {
      int2 p = pk0[e];
      float4 v = A4[(long)p.x * 64 + s];
      float nm = __int_as_float(p.y);
      float f[8]; unpack8(v, f);
#pragma unroll
      for (int c = 0; c < C; ++c) acc0[c] += nm * f[c];
    }
  }
  {
    int e = rp1[n], end = rp1[n + 1];
    for (; e + 2 <= end; e += 2) {
      int2 p0 = pk1[e], p1 = pk1[e + 1];
      float4 v0 = B4[(long)p0.x * 64 + s];
      float4 v1 = B4[(long)p1.x * 64 + s];
      float n0 = __int_as_float(p0.y), n1 = __int_as_float(p1.y);
      float f0[8], f1[8];
      unpack8(v0, f0); unpack8(v1, f1);
#pragma unroll
      for (int c = 0; c < C; ++c) acc1[c] += n0 * f0[c] + n1 * f1[c];
    }
    for (; e < end; ++e) {
      int2 p = pk1[e];
      float4 v = B4[(long)p.x * 64 + s];
      float nm = __int_as_float(p.y);
      float f[8]; unpack8(v, f);
#pragma unroll
      for (int c = 0; c < C; ++c) acc1[c] += nm * f[c];
    }
  }
  float z[C];
#pragma unroll
  for (int d = 0; d < C; ++d) z[d] = bs[d];
  {
    float xv[8], av[8], bv[8];
    unpack8(reinterpret_cast<const float4*>(Xh)[tid], xv);
    unpack8(A4[tid], av);
    unpack8(B4[tid], bv);
#pragma unroll
    for (int c = 0; c < C; ++c) {
      float x0c = xv[c], tac = av[c], tbc = bv[c], a0 = acc0[c], a1 = acc1[c];
#pragma unroll
      for (int d = 0; d < C; ++d)
        z[d] += x0c * wx[c * C + d] + tac * w1a[c * C + d] + tbc * w1b[c * C + d] +
                a0 * w2a[c * C + d] + a1 * w2b[c * C + d];
    }
  }
  reinterpret_cast<float4*>(g ? outT : outH)[tid] = pack8(z);
}

// ---------------- block2 align(1x1)+GLU, rank-1-update form + occupancy bound ----------------
__global__ __launch_bounds__(256, 4) void glu2_kernel(const __half* __restrict__ H, const __half* __restrict__ Tt,
                                                      const float* __restrict__ w2, const float* __restrict__ b2,
                                                      const float* __restrict__ aw, const float* __restrict__ ab,
                                                      __half* __restrict__ X2nh) {
  __shared__ float wpq[48 * 24];   // 4.5 KB
  __shared__ float awl[16 * 12];   // 768 B
  __shared__ float bpq[22], bal[11];
  for (int i = threadIdx.x; i < 48 * 24; i += 256) {
    int k = i / 24, co = i - (i / 24) * 24;
    int tap = k >> 4, ci = k & 15;
    wpq[i] = (co < 22) ? w2[(co * 16 + ci) * 3 + tap] : 0.f;
  }
  for (int i = threadIdx.x; i < 16 * 12; i += 256) {
    int ci = i / 12, co = i - ci * 12;
    awl[i] = (co < 11) ? aw[co * 16 + ci] : 0.f;
  }
  if (threadIdx.x < 22) bpq[threadIdx.x] = b2[threadIdx.x];
  if (threadIdx.x < 11) bal[threadIdx.x] = ab[threadIdx.x];
  __syncthreads();
  int idx = blockIdx.x * 256 + threadIdx.x;   // idx = n*32 + s2, s2 = b*2 + t
  int n = idx >> 5, s = idx & 31;
  int bb = s >> 1, t = s & 1;
  long rbase = (long)n * 64 + bb * 4 + t;     // float4 row index (8 halfs per slice)
  const float4* H4 = reinterpret_cast<const float4*>(H) + rbase;
  const float4* T4 = reinterpret_cast<const float4*>(Tt) + rbase;
  float acc[24];        // [p0..p10 q0..q10 pad pad]
  float aac[12];
#pragma unroll
  for (int i = 0; i < 24; ++i) acc[i] = 0.f;
#pragma unroll
  for (int i = 0; i < 12; ++i) aac[i] = 0.f;
#pragma unroll
  for (int tap = 0; tap < 3; ++tap) {
    float hv8[8], tv8[8];
    unpack8(H4[tap], hv8);
    unpack8(T4[tap], tv8);
#pragma unroll
    for (int half_ = 0; half_ < 2; ++half_) {
#pragma unroll
      for (int c8 = 0; c8 < 8; ++c8) {
        float v = half_ ? tv8[c8] : hv8[c8];
        const float4* w4 = reinterpret_cast<const float4*>(&wpq[(tap * 16 + half_ * 8 + c8) * 24]);
#pragma unroll
        for (int j = 0; j < 6; ++j) {
          float4 wv = w4[j];
          acc[4 * j + 0] = fmaf(v, wv.x, acc[4 * j + 0]);
          acc[4 * j + 1] = fmaf(v, wv.y, acc[4 * j + 1]);
          acc[4 * j + 2] = fmaf(v, wv.z, acc[4 * j + 2]);
          acc[4 * j + 3] = fmaf(v, wv.w, acc[4 * j + 3]);
        }
        if (tap == 2) {
          const float4* a4 = reinterpret_cast<const float4*>(&awl[(half_ * 8 + c8) * 12]);
#pragma unroll
          for (int j = 0; j < 3; ++j) {
            float4 wv = a4[j];
            aac[4 * j + 0] = fmaf(v, wv.x, aac[4 * j + 0]);
            aac[4 * j + 1] = fmaf(v, wv.y, aac[4 * j + 1]);
            aac[4 * j + 2] = fmaf(v, wv.z, aac[4 * j + 2]);
            aac[4 * j + 3] = fmaf(v, wv.w, aac[4 * j + 3]);
          }
        }
      }
    }
  }
  float o[12];
  o[11] = 0.f;
#pragma unroll
  for (int co = 0; co < 11; ++co) {
    float p = acc[co] + bpq[co] + aac[co] + bal[co];
    float q = acc[co + 11] + bpq[co + 11];
    o[co] = p * sigmoidf_(q);
  }
  float2* o2 = reinterpret_cast<float2*>(X2nh) + (long)idx * 3;
  o2[0] = pack4(o);
  o2[1] = pack4(o + 4);
  o2[2] = pack4(o + 8);
}

// ---------------- block2 pull (batched: all 4 lists gather the SHARED X2nh buffer) ----------------
__global__ __launch_bounds__(256) void pull2_kernel(const int* __restrict__ csrBase,
                                                    const __half* __restrict__ Xh,
                                                    __half* __restrict__ T1hAll) {
  int gtid = blockIdx.x * 256 + threadIdx.x;
  int l = gtid / (NN * 96);
  int t = gtid - l * (NN * 96);
  int n = t / 96, j = t - n * 96;
  const int* rp = CSR_RP(csrBase, l);
  const int2* pk = CSR_PK(csrBase, l);
  const float2* in2 = reinterpret_cast<const float2*>(Xh);
  float acc[4];
#pragma unroll
  for (int i = 0; i < 4; ++i) acc[i] = 0.f;
  int e = rp[n], end = rp[n + 1];
  for (; e + 4 <= end; e += 4) {
    int2 p0 = pk[e], p1 = pk[e + 1], p2 = pk[e + 2], p3 = pk[e + 3];
    float2 v0 = in2[(long)p0.x * 96 + j];
    float2 v1 = in2[(long)p1.x * 96 + j];
    float2 v2 = in2[(long)p2.x * 96 + j];
    float2 v3 = in2[(long)p3.x * 96 + j];
    float f[4];
    float n0 = __int_as_float(p0.y), n1 = __int_as_float(p1.y);
    float n2 = __int_as_float(p2.y), n3 = __int_as_float(p3.y);
    unpack4(v0, f);
#pragma unroll
    for (int i = 0; i < 4; ++i) acc[i] -= n0 * f[i];
    unpack4(v1, f);
#pragma unroll
    for (int i = 0; i < 4; ++i) acc[i] -= n1 * f[i];
    unpack4(v2, f);
#pragma unroll
    for (int i = 0; i < 4; ++i) acc[i] -= n2 * f[i];
    unpack4(v3, f);
#pragma unroll
    for (int i = 0; i < 4; ++i) acc[i] -= n3 * f[i];
  }
  for (; e < end; ++e) {
    int2 p = pk[e];
    float2 v = in2[(long)p.x * 96 + j];
    float nm = __int_as_float(p.y);
    float f[4];
    unpack4(v, f);
#pragma unroll
    for (int i = 0; i < 4; ++i) acc[i] -= nm * f[i];
  }
  reinterpret_cast<float2*>(T1hAll)[(size_t)l * (T1SLOT / 4) + t] = pack4(acc);
}

// ---------------- block2 fused Cheb combine (round-6: both graphs, both etypes, single write) ----
__global__ __launch_bounds__(256) void cheb2_kernel(const int* __restrict__ csrBase,
    const __half* __restrict__ Xh, const __half* __restrict__ T1hAll,
    const float* __restrict__ Whg, const float* __restrict__ bhg,
    const float* __restrict__ Wtg, const float* __restrict__ btg,
    __half* __restrict__ outH, __half* __restrict__ outT) {
  constexpr int C = 11, CC = 121;
  __shared__ float wx[CC], w1a[CC], w1b[CC], w2a[CC], w2b[CC], bs[C];
  int gtid = blockIdx.x * 256 + threadIdx.x;
  int g = gtid / (NN * 32);
  int tid = gtid - g * (NN * 32);
  const float* W = g ? Wtg : Whg;
  const float* bias = g ? btg : bhg;
  for (int i = threadIdx.x; i < CC; i += 256) {
    float w0A = W[i], w1A = W[CC + i], w2A = W[2 * CC + i];
    float w0B = W[3 * CC + i], w1B = W[4 * CC + i], w2B = W[5 * CC + i];
    wx[i] = w0A - w2A + w0B - w2B;
    w1a[i] = w1A; w1b[i] = w1B;
    w2a[i] = -2.f * w2A; w2b[i] = -2.f * w2B;
  }
  if (threadIdx.x < C) bs[threadIdx.x] = bias[threadIdx.x] + bias[C + threadIdx.x];
  __syncthreads();
  int n = tid >> 5, s = tid & 31;
  int s3 = s * 3;
  int l0 = 2 * g, l1 = 2 * g + 1;
  const int* rp0 = CSR_RP(csrBase, l0); const int2* pk0 = CSR_PK(csrBase, l0);
  const int* rp1 = CSR_RP(csrBase, l1); const int2* pk1 = CSR_PK(csrBase, l1);
  const float2* A2v = reinterpret_cast<const float2*>(T1hAll + (size_t)l0 * T1SLOT);
  const float2* B2v = reinterpret_cast<const float2*>(T1hAll + (size_t)l1 * T1SLOT);
  float acc0[12], acc1[12];
#pragma unroll
  for (int c = 0; c < 12; ++c) { acc0[c] = 0.f; acc1[c] = 0.f; }
  {
    int e = rp0[n], end = rp0[n + 1];
    for (; e + 2 <= end; e += 2) {
      int2 p0 = pk0[e], p1 = pk0[e + 1];
      long r0 = (long)p0.x * 96 + s3, r1 = (long)p1.x * 96 + s3;
      float2 a0 = A2v[r0], a1 = A2v[r0 + 1], a2 = A2v[r0 + 2];
      float2 b0 = A2v[r1], b1 = A2v[r1 + 1], b2 = A2v[r1 + 2];
      float n0 = __int_as_float(p0.y), n1 = __int_as_float(p1.y);
      float f[4];
      unpack4(a0, f);
#pragma unroll
      for (int i = 0; i < 4; ++i) acc0[i] += n0 * f[i];
      unpack4(a1, f);
#pragma unroll
      for (int i = 0; i < 4; ++i) acc0[4 + i] += n0 * f[i];
      unpack4(a2, f);
#pragma unroll
      for (int i = 0; i < 4; ++i) acc0[8 + i] += n0 * f[i];
      unpack4(b0, f);
#pragma unroll
      for (int i = 0; i < 4; ++i) acc0[i] += n1 * f[i];
      unpack4(b1, f);
#pragma unroll
      for (int i = 0; i < 4; ++i) acc0[4 + i] += n1 * f[i];
      unpack4(b2, f);
#pragma unroll
      for (int i = 0; i < 4; ++i) acc0[8 + i] += n1 * f[i];
    }
    for (; e < end; ++e) {
      int2 p = pk0[e];
      long r = (long)p.x * 96 + s3;
      float2 a0 = A2v[r], a1 = A2v[r + 1], a2 = A2v[r + 2];
      float nm = __int_as_float(p.y);
      float f[4];
      unpack4(a0, f);
#pragma unroll
      for (int i = 0; i < 4; ++i) acc0[i] += nm * f[i];
      unpack4(a1, f);
#pragma unroll
      for (int i = 0; i < 4; ++i) acc0[4 + i] += nm * f[i];
      unpack4(a2, f);
#pragma unroll
      for (int i = 0; i < 4; ++i) acc0[8 + i] += nm * f[i];
    }
  }
  {
    int e = rp1[n], end = rp1[n + 1];
    for (; e + 2 <= end; e += 2) {
      int2 p0 = pk1[e], p1 = pk1[e + 1];
      long r0 = (long)p0.x * 96 + s3, r1 = (long)p1.x * 96 + s3;
      float2 a0 = B2v[r0], a1 = B2v[r0 + 1], a2 = B2v[r0 + 2];
      float2 b0 = B2v[r1], b1 = B2v[r1 + 1], b2 = B2v[r1 + 2];
      float n0 = __int_as_float(p0.y), n1 = __int_as_float(p1.y);
      float f[4];
      unpack4(a0, f);
#pragma unroll
      for (int i = 0; i < 4; ++i) acc1[i] += n0 * f[i];
      unpack4(a1, f);
#pragma unroll
      for (int i = 0; i < 4; ++i) acc1[4 + i] += n0 * f[i];
      unpack4(a2, f);
#pragma unroll
      for (int i = 0; i < 4; ++i) acc1[8 + i] += n0 * f[i];
      unpack4(b0, f);
#pragma unroll
      for (int i = 0; i < 4; ++i) acc1[i] += n1 * f[i];
      unpack4(b1, f);
#pragma unroll
      for (int i = 0; i < 4; ++i) acc1[4 + i] += n1 * f[i];
      unpack4(b2, f);
#pragma unroll
      for (int i = 0; i < 4; ++i) acc1[8 + i] += n1 * f[i];
    }
    for (; e < end; ++e) {
      int2 p = pk1[e];
      long r = (long)p.x * 96 + s3;
      float2 a0 = B2v[r], a1 = B2v[r + 1], a2 = B2v[r + 2];
      float nm = __int_as_float(p.y);
      float f[4];
      unpack4(a0, f);
#pragma unroll
      for (int i = 0; i < 4; ++i) acc1[i] += nm * f[i];
      unpack4(a1, f);
#pragma unroll
      for (int i = 0; i < 4; ++i) acc1[4 + i] += nm * f[i];
      unpack4(a2, f);
#pragma unroll
      for (int i = 0; i < 4; ++i) acc1[8 + i] += nm * f[i];
    }
  }
  float z[12];
#pragma unroll
  for (int d = 0; d < C; ++d) z[d] = bs[d];
  z[11] = 0.f;
  const float2* X2v = reinterpret_cast<const float2*>(Xh);
  long own = (long)tid * 3;
#pragma unroll
  for (int q = 0; q < 3; ++q) {
    float xv[4], av[4], bv[4];
    unpack4(X2v[own + q], xv);
    unpack4(A2v[own + q], av);
    unpack4(B2v[own + q], bv);
#pragma unroll
    for (int k = 0; k < 4; ++k) {
      int c = q * 4 + k;
      if (c == 11) continue;
      float x0c = xv[k], tac = av[k], tbc = bv[k], a0 = acc0[c], a1 = acc1[c];
#pragma unroll
      for (int d = 0; d < C; ++d)
        z[d] += x0c * wx[c * C + d] + tac * w1a[c * C + d] + tbc * w1b[c * C + d] +
                a0 * w2a[c * C + d] + a1 * w2b[c * C + d];
    }
  }
  float2* o2 = reinterpret_cast<float2*>(g ? outT : outH) + (long)tid * 3;
  o2[0] = pack4(z);
  o2[1] = pack4(z + 4);
  o2[2] = pack4(z + 8);
}

// ---------------- final: grid-stride; fp16->fp32 conversion ONCE during LDS staging ----------------
__global__ __launch_bounds__(256) void final_kernel(const __half* __restrict__ H2, const __half* __restrict__ T2b,
                                                    const float* __restrict__ W, const float* __restrict__ bias,
                                                    float* __restrict__ out) {
  __shared__ float zsr[64][48];   // 12 KB: z rows pre-converted to fp32
  int tid = threadIdx.x;
  int c = tid & 127, h = tid >> 7;
  float wp[48];
#pragma unroll
  for (int off = 0; off < 48; ++off) {
    int half_ = off / 24, r_ = off - half_ * 24;
    int t = r_ / 12, c_ = r_ - t * 12;
    wp[off] = (c_ == 11) ? 0.f : W[(2 * (c_ + half_ * 11) + t) * 128 + c];
  }
  float bh = bias[c];
  for (int tile = blockIdx.x; tile < 7500; tile += gridDim.x) {
    long r0 = (long)tile * 64;
    __syncthreads();
#pragma unroll
    for (int it = 0; it < 2; ++it) {
      int item = it * 256 + tid;          // 384 items = 64 rows x 6 float4 (8 halfs each)
      if (item < 384) {
        int row = item / 6, piece = item - row * 6;
        long r = r0 + row;
        int b = (int)(r / NN), n = (int)(r - (long)b * NN);
        const float4* srcb = reinterpret_cast<const float4*>(piece < 3 ? H2 : T2b);
        int f4i = (piece < 3) ? piece : piece - 3;
        float4 v = srcb[(long)n * 48 + b * 3 + f4i];
        float f[8];
        unpack8(v, f);
        float4* d = reinterpret_cast<float4*>(&zsr[row][(piece < 3 ? 0 : 24) + f4i * 8]);
        d[0] = make_float4(f[0], f[1], f[2], f[3]);
        d[1] = make_float4(f[4], f[5], f[6], f[7]);
      }
    }
    __syncthreads();
    int rbeg = h * 32;
#pragma unroll 2
    for (int row = rbeg; row < rbeg + 32; ++row) {
      const float4* zr4 = reinterpret_cast<const float4*>(&zsr[row][0]);
      float acc = bh;
#pragma unroll
      for (int q = 0; q < 12; ++q) {
        float4 zv = zr4[q];
        acc = fmaf(zv.x, wp[4 * q + 0], acc);
        acc = fmaf(zv.y, wp[4 * q + 1], acc);
        acc = fmaf(zv.z, wp[4 * q + 2], acc);
        acc = fmaf(zv.w, wp[4 * q + 3], acc);
      }
      out[(r0 + row) * 128 + c] = acc;
    }
  }
}

extern "C" void kernel_launch(void* const* d_in, const int* in_sizes, int n_in,
                              void* d_out, int out_size, void* d_ws, size_t ws_size,
                              hipStream_t stream) {
  const float* x    = (const float*)d_in[0];
  const int*   hg   = (const int*)d_in[1];
  const int*   tg   = (const int*)d_in[2];
  const float* t1w  = (const float*)d_in[3];
  const float* t1b  = (const float*)d_in[4];
  const float* h1W  = (const float*)d_in[5];
  const float* h1b  = (const float*)d_in[6];
  const float* g1W  = (const float*)d_in[7];
  const float* g1b  = (const float*)d_in[8];
  const float* a2w  = (const float*)d_in[9];
  const float* a2b  = (const float*)d_in[10];
  const float* t2w  = (const float*)d_in[11];
  const float* t2b  = (const float*)d_in[12];
  const float* h2W  = (const float*)d_in[13];
  const float* h2b  = (const float*)d_in[14];
  const float* g2W  = (const float*)d_in[15];
  const float* g2b  = (const float*)d_in[16];
  const float* outw = (const float*)d_in[17];
  const float* outb = (const float*)d_in[18];
  float* out = (float*)d_out;

  // workspace layout (round-6 structure)
  __half* T1h = (__half*)d_ws;                 // 4 slots x T1SLOT halfs (pull outputs)
  __half* Xh  = T1h + 4L * T1SLOT;             // X1 [N][64][8] -> X2n [N][32][12]
  __half* Cfh = Xh + T1SLOT;                   // block1 H out -> block2 H out
  __half* Dfh = Cfh + T1SLOT;                  // block1 T out -> block2 T out
  int* csrBase  = (int*)(Dfh + T1SLOT);        // 4 * CSR_STRIDE ints
  int* degO     = csrBase + 4 * CSR_STRIDE;    // 4*NN
  int* degI     = degO + 4 * NN;               // 4*NN
  int* cursor   = degI + 4 * NN;               // 4*NN
  int* partials = cursor + 4 * NN;             // 4*NCH

  // --- build CSR (sorted by dst) + norms for all 4 edge lists, batched ---
  hipMemsetAsync(degO, 0, 8 * NN * sizeof(int), stream);
  count_all_kernel<<<(4 * EDGES + 255) / 256, 256, 0, stream>>>(hg, tg, degO, degI);
  scan1_kernel<<<4 * NCH, 256, 0, stream>>>(degI, csrBase, partials);
  scan2_kernel<<<1, 128, 0, stream>>>(partials);
  fixup_kernel<<<4 * NCH, 256, 0, stream>>>(csrBase, cursor, partials);
  fill_all_kernel<<<(4 * EDGES + 255) / 256, 256, 0, stream>>>(hg, tg, degO, degI, cursor, csrBase);

  // --- block1 ---
  glu1_kernel<<<NN * 64 / 256, 256, 0, stream>>>(x, t1w, t1b, Xh);
  pull1_kernel<<<4 * NN * 64 / 256, 256, 0, stream>>>(csrBase, Xh, T1h);
  cheb1_kernel<<<2 * NN * 64 / 256, 256, 0, stream>>>(csrBase, Xh, T1h, h1W, h1b, g1W, g1b, Cfh, Dfh);

  // --- block2 ---
  glu2_kernel<<<NN * 32 / 256, 256, 0, stream>>>(Cfh, Dfh, t2w, t2b, a2w, a2b, Xh);
  pull2_kernel<<<4 * NN * 96 / 256, 256, 0, stream>>>(csrBase, Xh, T1h);
  cheb2_kernel<<<2 * NN * 32 / 256, 256, 0, stream>>>(csrBase, Xh, T1h, h2W, h2b, g2W, g2b, Cfh, Dfh);

  // --- final linear ---
  final_kernel<<<1024, 256, 0, stream>>>(Cfh, Dfh, outw, outb, out);
}

// Round 14
// 788.927 us; speedup vs baseline: 1.7640x; 1.7640x over previous
//
#include <hip/hip_runtime.h>
#include <hip/hip_fp16.h>
#include <math.h>

#define EDGES 120000
#define NN    30000
#define NCH   118   // ceil(30000/256)
#define T1SLOT 15360000   // halfs per slot (NN*64*8)

__device__ __forceinline__ float sigmoidf_(float x) { return 1.f / (1.f + __expf(-x)); }

union F4H8 { float4 v; __half h[8]; };
union F2H4 { float2 v; __half h[4]; };

__device__ __forceinline__ void unpack8(float4 v, float* f) {
  F4H8 u; u.v = v;
#pragma unroll
  for (int i = 0; i < 8; ++i) f[i] = __half2float(u.h[i]);
}
__device__ __forceinline__ float4 pack8(const float* f) {
  F4H8 u;
#pragma unroll
  for (int i = 0; i < 8; ++i) u.h[i] = __float2half(f[i]);
  return u.v;
}
__device__ __forceinline__ void unpack4(float2 v, float* f) {
  F2H4 u; u.v = v;
#pragma unroll
  for (int i = 0; i < 4; ++i) f[i] = __half2float(u.h[i]);
}
__device__ __forceinline__ float2 pack4(const float* f) {
  F2H4 u;
#pragma unroll
  for (int i = 0; i < 4; ++i) u.h[i] = __float2half(f[i]);
  return u.v;
}

// CSR slot layout (ints): rowptr[30016] | pack int2[120000] (src, norm-bits)
#define CSR_STRIDE 270016
#define CSR_RP(base, l)   ((base) + (size_t)(l) * CSR_STRIDE)
#define CSR_PK(base, l)   ((const int2*)((base) + (size_t)(l) * CSR_STRIDE + 30016))
#define CSR_PKW(base, l)  ((int2*)((base) + (size_t)(l) * CSR_STRIDE + 30016))

// ---------------- CSR build ----------------
__global__ void count_all_kernel(const int* __restrict__ hg, const int* __restrict__ tg,
                                 int* __restrict__ degO, int* __restrict__ degI) {
  int tid = blockIdx.x * blockDim.x + threadIdx.x;
  if (tid >= 4 * EDGES) return;
  int l = tid / EDGES, j = tid - l * EDGES;
  const int* G = (l < 2) ? hg : tg;
  const int* src = G + (size_t)(l & 1) * 2 * EDGES;
  const int* dst = src + EDGES;
  atomicAdd(&degO[l * NN + src[j]], 1);
  atomicAdd(&degI[l * NN + dst[j]], 1);
}

__global__ __launch_bounds__(256) void scan1_kernel(const int* __restrict__ degI,
                                                    int* __restrict__ csrBase,
                                                    int* __restrict__ partials) {
  int l = blockIdx.x / NCH, ch = blockIdx.x - l * NCH;
  int tid = threadIdx.x;
  int i = ch * 256 + tid;
  __shared__ int buf[256];
  int v = (i < NN) ? degI[l * NN + i] : 0;
  buf[tid] = v;
  __syncthreads();
  for (int off = 1; off < 256; off <<= 1) {
    int t = (tid >= off) ? buf[tid - off] : 0;
    __syncthreads();
    buf[tid] += t;
    __syncthreads();
  }
  int* rp = CSR_RP(csrBase, l);
  if (i < NN) rp[i + 1] = buf[tid];
  if (tid == 255) partials[l * NCH + ch] = buf[255];
}

__global__ __launch_bounds__(128) void scan2_kernel(int* __restrict__ partials) {
  __shared__ int buf[128];
  int tid = threadIdx.x;
  for (int l = 0; l < 4; ++l) {
    int v = (tid < NCH) ? partials[l * NCH + tid] : 0;
    buf[tid] = v;
    __syncthreads();
    for (int off = 1; off < 128; off <<= 1) {
      int t = (tid >= off) ? buf[tid - off] : 0;
      __syncthreads();
      buf[tid] += t;
      __syncthreads();
    }
    if (tid < NCH) partials[l * NCH + tid] = buf[tid] - v;  // exclusive
    __syncthreads();
  }
}

__global__ __launch_bounds__(256) void fixup_kernel(int* __restrict__ csrBase,
                                                    int* __restrict__ cursor,
                                                    const int* __restrict__ partials) {
  int l = blockIdx.x / NCH, ch = blockIdx.x - l * NCH;
  int i = ch * 256 + threadIdx.x;
  int* rp = CSR_RP(csrBase, l);
  int off = partials[l * NCH + ch];
  if (i < NN) {
    int val = rp[i + 1] + off;
    rp[i + 1] = val;
    if (i + 1 < NN) cursor[l * NN + i + 1] = val;
  }
  if (i == 0) { rp[0] = 0; cursor[l * NN] = 0; }
}

__global__ void fill_all_kernel(const int* __restrict__ hg, const int* __restrict__ tg,
                                const int* __restrict__ degO, const int* __restrict__ degI,
                                int* __restrict__ cursor, int* __restrict__ csrBase) {
  int tid = blockIdx.x * blockDim.x + threadIdx.x;
  if (tid >= 4 * EDGES) return;
  int l = tid / EDGES, j = tid - l * EDGES;
  const int* G = (l < 2) ? hg : tg;
  const int* src = G + (size_t)(l & 1) * 2 * EDGES;
  const int* dst = src + EDGES;
  int s = src[j], d = dst[j];
  int doo = degO[l * NN + s]; if (doo < 1) doo = 1;
  int dii = degI[l * NN + d]; if (dii < 1) dii = 1;
  float nm = rsqrtf((float)doo) * rsqrtf((float)dii);
  int p = atomicAdd(&cursor[l * NN + d], 1);
  CSR_PKW(csrBase, l)[p] = make_int2(s, __float_as_int(nm));
}

// ---------------- block1 temporal GLU conv: x[B,N,6,1] -> X1h [N][64][8] fp16 ----------------
__global__ void glu1_kernel(const float* __restrict__ x, const float* __restrict__ w,
                            const float* __restrict__ b, __half* __restrict__ X1h) {
  int idx = blockIdx.x * blockDim.x + threadIdx.x;   // idx = n*64 + s, s = b*4 + t
  if (idx >= NN * 64) return;
  int n = idx >> 6, s = idx & 63;
  int bb = s >> 2, t = s & 3;
  const float* xb = x + ((long)bb * NN + n) * 6;
  float x0 = xb[t], x1 = xb[t + 1], x2 = xb[t + 2];
  float o[8];
#pragma unroll
  for (int c = 0; c < 8; ++c) {
    float p = w[c * 3 + 0] * x0 + w[c * 3 + 1] * x1 + w[c * 3 + 2] * x2 + b[c];
    float q = w[(c + 8) * 3 + 0] * x0 + w[(c + 8) * 3 + 1] * x1 + w[(c + 8) * 3 + 2] * x2 + b[c + 8];
    float al = (c == 0) ? x2 : 0.f;
    o[c] = (p + al) * sigmoidf_(q);
  }
  reinterpret_cast<float4*>(X1h)[idx] = pack8(o);
}

// ---------------- block1 pull (batched: all 4 lists gather the SHARED X1 buffer) ----------------
__global__ __launch_bounds__(256) void pull1_kernel(const int* __restrict__ csrBase,
                                                    const __half* __restrict__ Xh,
                                                    __half* __restrict__ T1hAll) {
  int gtid = blockIdx.x * 256 + threadIdx.x;
  int l = gtid / (NN * 64);
  int t = gtid - l * (NN * 64);
  int n = t >> 6, j = t & 63;
  const int* rp = CSR_RP(csrBase, l);
  const int2* pk = CSR_PK(csrBase, l);
  const float4* in4 = reinterpret_cast<const float4*>(Xh);
  float acc[8];
#pragma unroll
  for (int i = 0; i < 8; ++i) acc[i] = 0.f;
  int e = rp[n], end = rp[n + 1];
  for (; e + 4 <= end; e += 4) {
    int2 p0 = pk[e], p1 = pk[e + 1], p2 = pk[e + 2], p3 = pk[e + 3];
    float4 v0 = in4[(long)p0.x * 64 + j];
    float4 v1 = in4[(long)p1.x * 64 + j];
    float4 v2 = in4[(long)p2.x * 64 + j];
    float4 v3 = in4[(long)p3.x * 64 + j];
    float f[8];
    float n0 = __int_as_float(p0.y), n1 = __int_as_float(p1.y);
    float n2 = __int_as_float(p2.y), n3 = __int_as_float(p3.y);
    unpack8(v0, f);
#pragma unroll
    for (int i = 0; i < 8; ++i) acc[i] -= n0 * f[i];
    unpack8(v1, f);
#pragma unroll
    for (int i = 0; i < 8; ++i) acc[i] -= n1 * f[i];
    unpack8(v2, f);
#pragma unroll
    for (int i = 0; i < 8; ++i) acc[i] -= n2 * f[i];
    unpack8(v3, f);
#pragma unroll
    for (int i = 0; i < 8; ++i) acc[i] -= n3 * f[i];
  }
  for (; e < end; ++e) {
    int2 p = pk[e];
    float4 v = in4[(long)p.x * 64 + j];
    float nm = __int_as_float(p.y);
    float f[8];
    unpack8(v, f);
#pragma unroll
    for (int i = 0; i < 8; ++i) acc[i] -= nm * f[i];
  }
  reinterpret_cast<float4*>(T1hAll)[(size_t)l * (T1SLOT / 8) + t] = pack8(acc);
}

// ---------------- block1 fused Cheb combine (round-6: both graphs, both etypes) ----------------
__global__ __launch_bounds__(256) void cheb1_kernel(const int* __restrict__ csrBase,
    const __half* __restrict__ Xh, const __half* __restrict__ T1hAll,
    const float* __restrict__ Whg, const float* __restrict__ bhg,
    const float* __restrict__ Wtg, const float* __restrict__ btg,
    __half* __restrict__ outH, __half* __restrict__ outT) {
  constexpr int C = 8, CC = 64;
  __shared__ float wx[CC], w1a[CC], w1b[CC], w2a[CC], w2b[CC], bs[C];
  int gtid = blockIdx.x * 256 + threadIdx.x;
  int g = gtid / (NN * 64);
  int tid = gtid - g * (NN * 64);
  const float* W = g ? Wtg : Whg;
  const float* bias = g ? btg : bhg;
  for (int i = threadIdx.x; i < CC; i += 256) {
    float w0A = W[i], w1A = W[CC + i], w2A = W[2 * CC + i];
    float w0B = W[3 * CC + i], w1B = W[4 * CC + i], w2B = W[5 * CC + i];
    wx[i] = w0A - w2A + w0B - w2B;
    w1a[i] = w1A; w1b[i] = w1B;
    w2a[i] = -2.f * w2A; w2b[i] = -2.f * w2B;
  }
  if (threadIdx.x < C) bs[threadIdx.x] = bias[threadIdx.x] + bias[C + threadIdx.x];
  __syncthreads();
  int n = tid >> 6, s = tid & 63;
  int l0 = 2 * g, l1 = 2 * g + 1;
  const int* rp0 = CSR_RP(csrBase, l0); const int2* pk0 = CSR_PK(csrBase, l0);
  const int* rp1 = CSR_RP(csrBase, l1); const int2* pk1 = CSR_PK(csrBase, l1);
  const float4* A4 = reinterpret_cast<const float4*>(T1hAll + (size_t)l0 * T1SLOT);
  const float4* B4 = reinterpret_cast<const float4*>(T1hAll + (size_t)l1 * T1SLOT);
  float acc0[C], acc1[C];
#pragma unroll
  for (int c = 0; c < C; ++c) { acc0[c] = 0.f; acc1[c] = 0.f; }
  {
    int e = rp0[n], end = rp0[n + 1];
    for (; e + 2 <= end; e += 2) {
      int2 p0 = pk0[e], p1 = pk0[e + 1];
      float4 v0 = A4[(long)p0.x * 64 + s];
      float4 v1 = A4[(long)p1.x * 64 + s];
      float n0 = __int_as_float(p0.y), n1 = __int_as_float(p1.y);
      float f0[8], f1[8];
      unpack8(v0, f0); unpack8(v1, f1);
#pragma unroll
      for (int c = 0; c < C; ++c) acc0[c] += n0 * f0[c] + n1 * f1[c];
    }
    for (; e < end; ++e) {
      int2 p = pk0[e];
      float4 v = A4[(long)p.x * 64 + s];
      float nm = __int_as_float(p.y);
      float f[8]; unpack8(v, f);
#pragma unroll
      for (int c = 0; c < C; ++c) acc0[c] += nm * f[c];
    }
  }
  {
    int e = rp1[n], end = rp1[n + 1];
    for (; e + 2 <= end; e += 2) {
      int2 p0 = pk1[e], p1 = pk1[e + 1];
      float4 v0 = B4[(long)p0.x * 64 + s];
      float4 v1 = B4[(long)p1.x * 64 + s];
      float n0 = __int_as_float(p0.y), n1 = __int_as_float(p1.y);
      float f0[8], f1[8];
      unpack8(v0, f0); unpack8(v1, f1);
#pragma unroll
      for (int c = 0; c < C; ++c) acc1[c] += n0 * f0[c] + n1 * f1[c];
    }
    for (; e < end; ++e) {
      int2 p = pk1[e];
      float4 v = B4[(long)p.x * 64 + s];
      float nm = __int_as_float(p.y);
      float f[8]; unpack8(v, f);
#pragma unroll
      for (int c = 0; c < C; ++c) acc1[c] += nm * f[c];
    }
  }
  float z[C];
#pragma unroll
  for (int d = 0; d < C; ++d) z[d] = bs[d];
  {
    float xv[8], av[8], bv[8];
    unpack8(reinterpret_cast<const float4*>(Xh)[tid], xv);
    unpack8(A4[tid], av);
    unpack8(B4[tid], bv);
#pragma unroll
    for (int c = 0; c < C; ++c) {
      float x0c = xv[c], tac = av[c], tbc = bv[c], a0 = acc0[c], a1 = acc1[c];
#pragma unroll
      for (int d = 0; d < C; ++d)
        z[d] += x0c * wx[c * C + d] + tac * w1a[c * C + d] + tbc * w1b[c * C + d] +
                a0 * w2a[c * C + d] + a1 * w2b[c * C + d];
    }
  }
  reinterpret_cast<float4*>(g ? outT : outH)[tid] = pack8(z);
}

// ---------------- block2 align(1x1)+GLU, rank-1-update form, hoisting-capped ----------------
__global__ __launch_bounds__(256) void glu2_kernel(const __half* __restrict__ H, const __half* __restrict__ Tt,
                                                   const float* __restrict__ w2, const float* __restrict__ b2,
                                                   const float* __restrict__ aw, const float* __restrict__ ab,
                                                   __half* __restrict__ X2nh) {
  __shared__ float wpq[48 * 24];   // 4.5 KB
  __shared__ float awl[16 * 12];   // 768 B
  __shared__ float bpq[22], bal[11];
  for (int i = threadIdx.x; i < 48 * 24; i += 256) {
    int k = i / 24, co = i - (i / 24) * 24;
    int tap = k >> 4, ci = k & 15;
    wpq[i] = (co < 22) ? w2[(co * 16 + ci) * 3 + tap] : 0.f;
  }
  for (int i = threadIdx.x; i < 16 * 12; i += 256) {
    int ci = i / 12, co = i - ci * 12;
    awl[i] = (co < 11) ? aw[co * 16 + ci] : 0.f;
  }
  if (threadIdx.x < 22) bpq[threadIdx.x] = b2[threadIdx.x];
  if (threadIdx.x < 11) bal[threadIdx.x] = ab[threadIdx.x];
  __syncthreads();
  int idx = blockIdx.x * 256 + threadIdx.x;   // idx = n*32 + s2, s2 = b*2 + t
  int n = idx >> 5, s = idx & 31;
  int bb = s >> 1, t = s & 1;
  long rbase = (long)n * 64 + bb * 4 + t;     // float4 row index (8 halfs per slice)
  const float4* H4 = reinterpret_cast<const float4*>(H) + rbase;
  const float4* T4 = reinterpret_cast<const float4*>(Tt) + rbase;
  float acc[24];        // [p0..p10 q0..q10 pad pad]
  float aac[12];
#pragma unroll
  for (int i = 0; i < 24; ++i) acc[i] = 0.f;
#pragma unroll
  for (int i = 0; i < 12; ++i) aac[i] = 0.f;
#pragma unroll 1
  for (int tap = 0; tap < 3; ++tap) {
    float hv8[8], tv8[8];
    unpack8(H4[tap], hv8);
    unpack8(T4[tap], tv8);
#pragma unroll 1
    for (int half_ = 0; half_ < 2; ++half_) {
#pragma unroll
      for (int c8 = 0; c8 < 8; ++c8) {
        float v = half_ ? tv8[c8] : hv8[c8];
        const float4* w4 = reinterpret_cast<const float4*>(&wpq[(tap * 16 + half_ * 8 + c8) * 24]);
#pragma unroll
        for (int j = 0; j < 6; ++j) {
          float4 wv = w4[j];
          acc[4 * j + 0] = fmaf(v, wv.x, acc[4 * j + 0]);
          acc[4 * j + 1] = fmaf(v, wv.y, acc[4 * j + 1]);
          acc[4 * j + 2] = fmaf(v, wv.z, acc[4 * j + 2]);
          acc[4 * j + 3] = fmaf(v, wv.w, acc[4 * j + 3]);
        }
        if (tap == 2) {
          const float4* a4 = reinterpret_cast<const float4*>(&awl[(half_ * 8 + c8) * 12]);
#pragma unroll
          for (int j = 0; j < 3; ++j) {
            float4 wv = a4[j];
            aac[4 * j + 0] = fmaf(v, wv.x, aac[4 * j + 0]);
            aac[4 * j + 1] = fmaf(v, wv.y, aac[4 * j + 1]);
            aac[4 * j + 2] = fmaf(v, wv.z, aac[4 * j + 2]);
            aac[4 * j + 3] = fmaf(v, wv.w, aac[4 * j + 3]);
          }
        }
      }
    }
  }
  float o[12];
  o[11] = 0.f;
#pragma unroll
  for (int co = 0; co < 11; ++co) {
    float p = acc[co] + bpq[co] + aac[co] + bal[co];
    float q = acc[co + 11] + bpq[co + 11];
    o[co] = p * sigmoidf_(q);
  }
  float2* o2 = reinterpret_cast<float2*>(X2nh) + (long)idx * 3;
  o2[0] = pack4(o);
  o2[1] = pack4(o + 4);
  o2[2] = pack4(o + 8);
}

// ---------------- block2 pull (batched: all 4 lists gather the SHARED X2nh buffer) ----------------
__global__ __launch_bounds__(256) void pull2_kernel(const int* __restrict__ csrBase,
                                                    const __half* __restrict__ Xh,
                                                    __half* __restrict__ T1hAll) {
  int gtid = blockIdx.x * 256 + threadIdx.x;
  int l = gtid / (NN * 96);
  int t = gtid - l * (NN * 96);
  int n = t / 96, j = t - n * 96;
  const int* rp = CSR_RP(csrBase, l);
  const int2* pk = CSR_PK(csrBase, l);
  const float2* in2 = reinterpret_cast<const float2*>(Xh);
  float acc[4];
#pragma unroll
  for (int i = 0; i < 4; ++i) acc[i] = 0.f;
  int e = rp[n], end = rp[n + 1];
  for (; e + 4 <= end; e += 4) {
    int2 p0 = pk[e], p1 = pk[e + 1], p2 = pk[e + 2], p3 = pk[e + 3];
    float2 v0 = in2[(long)p0.x * 96 + j];
    float2 v1 = in2[(long)p1.x * 96 + j];
    float2 v2 = in2[(long)p2.x * 96 + j];
    float2 v3 = in2[(long)p3.x * 96 + j];
    float f[4];
    float n0 = __int_as_float(p0.y), n1 = __int_as_float(p1.y);
    float n2 = __int_as_float(p2.y), n3 = __int_as_float(p3.y);
    unpack4(v0, f);
#pragma unroll
    for (int i = 0; i < 4; ++i) acc[i] -= n0 * f[i];
    unpack4(v1, f);
#pragma unroll
    for (int i = 0; i < 4; ++i) acc[i] -= n1 * f[i];
    unpack4(v2, f);
#pragma unroll
    for (int i = 0; i < 4; ++i) acc[i] -= n2 * f[i];
    unpack4(v3, f);
#pragma unroll
    for (int i = 0; i < 4; ++i) acc[i] -= n3 * f[i];
  }
  for (; e < end; ++e) {
    int2 p = pk[e];
    float2 v = in2[(long)p.x * 96 + j];
    float nm = __int_as_float(p.y);
    float f[4];
    unpack4(v, f);
#pragma unroll
    for (int i = 0; i < 4; ++i) acc[i] -= nm * f[i];
  }
  reinterpret_cast<float2*>(T1hAll)[(size_t)l * (T1SLOT / 4) + t] = pack4(acc);
}

// ---------------- block2 fused Cheb combine (round-6: both graphs, both etypes, single write) ----
__global__ __launch_bounds__(256) void cheb2_kernel(const int* __restrict__ csrBase,
    const __half* __restrict__ Xh, const __half* __restrict__ T1hAll,
    const float* __restrict__ Whg, const float* __restrict__ bhg,
    const float* __restrict__ Wtg, const float* __restrict__ btg,
    __half* __restrict__ outH, __half* __restrict__ outT) {
  constexpr int C = 11, CC = 121;
  __shared__ float wx[CC], w1a[CC], w1b[CC], w2a[CC], w2b[CC], bs[C];
  int gtid = blockIdx.x * 256 + threadIdx.x;
  int g = gtid / (NN * 32);
  int tid = gtid - g * (NN * 32);
  const float* W = g ? Wtg : Whg;
  const float* bias = g ? btg : bhg;
  for (int i = threadIdx.x; i < CC; i += 256) {
    float w0A = W[i], w1A = W[CC + i], w2A = W[2 * CC + i];
    float w0B = W[3 * CC + i], w1B = W[4 * CC + i], w2B = W[5 * CC + i];
    wx[i] = w0A - w2A + w0B - w2B;
    w1a[i] = w1A; w1b[i] = w1B;
    w2a[i] = -2.f * w2A; w2b[i] = -2.f * w2B;
  }
  if (threadIdx.x < C) bs[threadIdx.x] = bias[threadIdx.x] + bias[C + threadIdx.x];
  __syncthreads();
  int n = tid >> 5, s = tid & 31;
  int s3 = s * 3;
  int l0 = 2 * g, l1 = 2 * g + 1;
  const int* rp0 = CSR_RP(csrBase, l0); const int2* pk0 = CSR_PK(csrBase, l0);
  const int* rp1 = CSR_RP(csrBase, l1); const int2* pk1 = CSR_PK(csrBase, l1);
  const float2* A2v = reinterpret_cast<const float2*>(T1hAll + (size_t)l0 * T1SLOT);
  const float2* B2v = reinterpret_cast<const float2*>(T1hAll + (size_t)l1 * T1SLOT);
  float acc0[12], acc1[12];
#pragma unroll
  for (int c = 0; c < 12; ++c) { acc0[c] = 0.f; acc1[c] = 0.f; }
  {
    int e = rp0[n], end = rp0[n + 1];
    for (; e + 2 <= end; e += 2) {
      int2 p0 = pk0[e], p1 = pk0[e + 1];
      long r0 = (long)p0.x * 96 + s3, r1 = (long)p1.x * 96 + s3;
      float2 a0 = A2v[r0], a1 = A2v[r0 + 1], a2 = A2v[r0 + 2];
      float2 b0 = A2v[r1], b1 = A2v[r1 + 1], b2 = A2v[r1 + 2];
      float n0 = __int_as_float(p0.y), n1 = __int_as_float(p1.y);
      float f[4];
      unpack4(a0, f);
#pragma unroll
      for (int i = 0; i < 4; ++i) acc0[i] += n0 * f[i];
      unpack4(a1, f);
#pragma unroll
      for (int i = 0; i < 4; ++i) acc0[4 + i] += n0 * f[i];
      unpack4(a2, f);
#pragma unroll
      for (int i = 0; i < 4; ++i) acc0[8 + i] += n0 * f[i];
      unpack4(b0, f);
#pragma unroll
      for (int i = 0; i < 4; ++i) acc0[i] += n1 * f[i];
      unpack4(b1, f);
#pragma unroll
      for (int i = 0; i < 4; ++i) acc0[4 + i] += n1 * f[i];
      unpack4(b2, f);
#pragma unroll
      for (int i = 0; i < 4; ++i) acc0[8 + i] += n1 * f[i];
    }
    for (; e < end; ++e) {
      int2 p = pk0[e];
      long r = (long)p.x * 96 + s3;
      float2 a0 = A2v[r], a1 = A2v[r + 1], a2 = A2v[r + 2];
      float nm = __int_as_float(p.y);
      float f[4];
      unpack4(a0, f);
#pragma unroll
      for (int i = 0; i < 4; ++i) acc0[i] += nm * f[i];
      unpack4(a1, f);
#pragma unroll
      for (int i = 0; i < 4; ++i) acc0[4 + i] += nm * f[i];
      unpack4(a2, f);
#pragma unroll
      for (int i = 0; i < 4; ++i) acc0[8 + i] += nm * f[i];
    }
  }
  {
    int e = rp1[n], end = rp1[n + 1];
    for (; e + 2 <= end; e += 2) {
      int2 p0 = pk1[e], p1 = pk1[e + 1];
      long r0 = (long)p0.x * 96 + s3, r1 = (long)p1.x * 96 + s3;
      float2 a0 = B2v[r0], a1 = B2v[r0 + 1], a2 = B2v[r0 + 2];
      float2 b0 = B2v[r1], b1 = B2v[r1 + 1], b2 = B2v[r1 + 2];
      float n0 = __int_as_float(p0.y), n1 = __int_as_float(p1.y);
      float f[4];
      unpack4(a0, f);
#pragma unroll
      for (int i = 0; i < 4; ++i) acc1[i] += n0 * f[i];
      unpack4(a1, f);
#pragma unroll
      for (int i = 0; i < 4; ++i) acc1[4 + i] += n0 * f[i];
      unpack4(a2, f);
#pragma unroll
      for (int i = 0; i < 4; ++i) acc1[8 + i] += n0 * f[i];
      unpack4(b0, f);
#pragma unroll
      for (int i = 0; i < 4; ++i) acc1[i] += n1 * f[i];
      unpack4(b1, f);
#pragma unroll
      for (int i = 0; i < 4; ++i) acc1[4 + i] += n1 * f[i];
      unpack4(b2, f);
#pragma unroll
      for (int i = 0; i < 4; ++i) acc1[8 + i] += n1 * f[i];
    }
    for (; e < end; ++e) {
      int2 p = pk1[e];
      long r = (long)p.x * 96 + s3;
      float2 a0 = B2v[r], a1 = B2v[r + 1], a2 = B2v[r + 2];
      float nm = __int_as_float(p.y);
      float f[4];
      unpack4(a0, f);
#pragma unroll
      for (int i = 0; i < 4; ++i) acc1[i] += nm * f[i];
      unpack4(a1, f);
#pragma unroll
      for (int i = 0; i < 4; ++i) acc1[4 + i] += nm * f[i];
      unpack4(a2, f);
#pragma unroll
      for (int i = 0; i < 4; ++i) acc1[8 + i] += nm * f[i];
    }
  }
  float z[12];
#pragma unroll
  for (int d = 0; d < C; ++d) z[d] = bs[d];
  z[11] = 0.f;
  const float2* X2v = reinterpret_cast<const float2*>(Xh);
  long own = (long)tid * 3;
#pragma unroll
  for (int q = 0; q < 3; ++q) {
    float xv[4], av[4], bv[4];
    unpack4(X2v[own + q], xv);
    unpack4(A2v[own + q], av);
    unpack4(B2v[own + q], bv);
#pragma unroll
    for (int k = 0; k < 4; ++k) {
      int c = q * 4 + k;
      if (c == 11) continue;
      float x0c = xv[k], tac = av[k], tbc = bv[k], a0 = acc0[c], a1 = acc1[c];
#pragma unroll
      for (int d = 0; d < C; ++d)
        z[d] += x0c * wx[c * C + d] + tac * w1a[c * C + d] + tbc * w1b[c * C + d] +
                a0 * w2a[c * C + d] + a1 * w2b[c * C + d];
    }
  }
  float2* o2 = reinterpret_cast<float2*>(g ? outT : outH) + (long)tid * 3;
  o2[0] = pack4(z);
  o2[1] = pack4(z + 4);
  o2[2] = pack4(z + 8);
}

// ---------------- final: grid-stride; fp16->fp32 conversion ONCE during LDS staging ----------------
__global__ __launch_bounds__(256) void final_kernel(const __half* __restrict__ H2, const __half* __restrict__ T2b,
                                                    const float* __restrict__ W, const float* __restrict__ bias,
                                                    float* __restrict__ out) {
  __shared__ float zsr[64][48];   // 12 KB: z rows pre-converted to fp32
  int tid = threadIdx.x;
  int c = tid & 127, h = tid >> 7;
  float wp[48];
#pragma unroll
  for (int off = 0; off < 48; ++off) {
    int half_ = off / 24, r_ = off - half_ * 24;
    int t = r_ / 12, c_ = r_ - t * 12;
    wp[off] = (c_ == 11) ? 0.f : W[(2 * (c_ + half_ * 11) + t) * 128 + c];
  }
  float bh = bias[c];
  for (int tile = blockIdx.x; tile < 7500; tile += gridDim.x) {
    long r0 = (long)tile * 64;
    __syncthreads();
#pragma unroll
    for (int it = 0; it < 2; ++it) {
      int item = it * 256 + tid;          // 384 items = 64 rows x 6 float4 (8 halfs each)
      if (item < 384) {
        int row = item / 6, piece = item - row * 6;
        long r = r0 + row;
        int b = (int)(r / NN), n = (int)(r - (long)b * NN);
        const float4* srcb = reinterpret_cast<const float4*>(piece < 3 ? H2 : T2b);
        int f4i = (piece < 3) ? piece : piece - 3;
        float4 v = srcb[(long)n * 48 + b * 3 + f4i];
        float f[8];
        unpack8(v, f);
        float4* d = reinterpret_cast<float4*>(&zsr[row][(piece < 3 ? 0 : 24) + f4i * 8]);
        d[0] = make_float4(f[0], f[1], f[2], f[3]);
        d[1] = make_float4(f[4], f[5], f[6], f[7]);
      }
    }
    __syncthreads();
    int rbeg = h * 32;
#pragma unroll 2
    for (int row = rbeg; row < rbeg + 32; ++row) {
      const float4* zr4 = reinterpret_cast<const float4*>(&zsr[row][0]);
      float acc = bh;
#pragma unroll
      for (int q = 0; q < 12; ++q) {
        float4 zv = zr4[q];
        acc = fmaf(zv.x, wp[4 * q + 0], acc);
        acc = fmaf(zv.y, wp[4 * q + 1], acc);
        acc = fmaf(zv.z, wp[4 * q + 2], acc);
        acc = fmaf(zv.w, wp[4 * q + 3], acc);
      }
      out[(r0 + row) * 128 + c] = acc;
    }
  }
}

extern "C" void kernel_launch(void* const* d_in, const int* in_sizes, int n_in,
                              void* d_out, int out_size, void* d_ws, size_t ws_size,
                              hipStream_t stream) {
  const float* x    = (const float*)d_in[0];
  const int*   hg   = (const int*)d_in[1];
  const int*   tg   = (const int*)d_in[2];
  const float* t1w  = (const float*)d_in[3];
  const float* t1b  = (const float*)d_in[4];
  const float* h1W  = (const float*)d_in[5];
  const float* h1b  = (const float*)d_in[6];
  const float* g1W  = (const float*)d_in[7];
  const float* g1b  = (const float*)d_in[8];
  const float* a2w  = (const float*)d_in[9];
  const float* a2b  = (const float*)d_in[10];
  const float* t2w  = (const float*)d_in[11];
  const float* t2b  = (const float*)d_in[12];
  const float* h2W  = (const float*)d_in[13];
  const float* h2b  = (const float*)d_in[14];
  const float* g2W  = (const float*)d_in[15];
  const float* g2b  = (const float*)d_in[16];
  const float* outw = (const float*)d_in[17];
  const float* outb = (const float*)d_in[18];
  float* out = (float*)d_out;

  // workspace layout (round-6 structure)
  __half* T1h = (__half*)d_ws;                 // 4 slots x T1SLOT halfs (pull outputs)
  __half* Xh  = T1h + 4L * T1SLOT;             // X1 [N][64][8] -> X2n [N][32][12]
  __half* Cfh = Xh + T1SLOT;                   // block1 H out -> block2 H out
  __half* Dfh = Cfh + T1SLOT;                  // block1 T out -> block2 T out
  int* csrBase  = (int*)(Dfh + T1SLOT);        // 4 * CSR_STRIDE ints
  int* degO     = csrBase + 4 * CSR_STRIDE;    // 4*NN
  int* degI     = degO + 4 * NN;               // 4*NN
  int* cursor   = degI + 4 * NN;               // 4*NN
  int* partials = cursor + 4 * NN;             // 4*NCH

  // --- build CSR (sorted by dst) + norms for all 4 edge lists, batched ---
  hipMemsetAsync(degO, 0, 8 * NN * sizeof(int), stream);
  count_all_kernel<<<(4 * EDGES + 255) / 256, 256, 0, stream>>>(hg, tg, degO, degI);
  scan1_kernel<<<4 * NCH, 256, 0, stream>>>(degI, csrBase, partials);
  scan2_kernel<<<1, 128, 0, stream>>>(partials);
  fixup_kernel<<<4 * NCH, 256, 0, stream>>>(csrBase, cursor, partials);
  fill_all_kernel<<<(4 * EDGES + 255) / 256, 256, 0, stream>>>(hg, tg, degO, degI, cursor, csrBase);

  // --- block1 ---
  glu1_kernel<<<NN * 64 / 256, 256, 0, stream>>>(x, t1w, t1b, Xh);
  pull1_kernel<<<4 * NN * 64 / 256, 256, 0, stream>>>(csrBase, Xh, T1h);
  cheb1_kernel<<<2 * NN * 64 / 256, 256, 0, stream>>>(csrBase, Xh, T1h, h1W, h1b, g1W, g1b, Cfh, Dfh);

  // --- block2 ---
  glu2_kernel<<<NN * 32 / 256, 256, 0, stream>>>(Cfh, Dfh, t2w, t2b, a2w, a2b, Xh);
  pull2_kernel<<<4 * NN * 96 / 256, 256, 0, stream>>>(csrBase, Xh, T1h);
  cheb2_kernel<<<2 * NN * 32 / 256, 256, 0, stream>>>(csrBase, Xh, T1h, h2W, h2b, g2W, g2b, Cfh, Dfh);

  // --- final linear ---
  final_kernel<<<1024, 256, 0, stream>>>(Cfh, Dfh, outw, outb, out);
}

// Round 15
// 780.775 us; speedup vs baseline: 1.7824x; 1.0104x over previous
//
#include <hip/hip_runtime.h>
#include <hip/hip_fp16.h>
#include <math.h>

#define EDGES 120000
#define NN    30000
#define NCH   118   // ceil(30000/256)
#define T1SLOT 15360000   // halfs per slot (NN*64*8)

__device__ __forceinline__ float sigmoidf_(float x) { return 1.f / (1.f + __expf(-x)); }

union F4H8 { float4 v; __half h[8]; };
union F2H4 { float2 v; __half h[4]; };

__device__ __forceinline__ void unpack8(float4 v, float* f) {
  F4H8 u; u.v = v;
#pragma unroll
  for (int i = 0; i < 8; ++i) f[i] = __half2float(u.h[i]);
}
__device__ __forceinline__ float4 pack8(const float* f) {
  F4H8 u;
#pragma unroll
  for (int i = 0; i < 8; ++i) u.h[i] = __float2half(f[i]);
  return u.v;
}
__device__ __forceinline__ void unpack4(float2 v, float* f) {
  F2H4 u; u.v = v;
#pragma unroll
  for (int i = 0; i < 4; ++i) f[i] = __half2float(u.h[i]);
}
__device__ __forceinline__ float2 pack4(const float* f) {
  F2H4 u;
#pragma unroll
  for (int i = 0; i < 4; ++i) u.h[i] = __float2half(f[i]);
  return u.v;
}

// CSR slot layout (ints): rowptr[30016] | pack int2[120000] (src, norm-bits)
#define CSR_STRIDE 270016
#define CSR_RP(base, l)   ((base) + (size_t)(l) * CSR_STRIDE)
#define CSR_PK(base, l)   ((const int2*)((base) + (size_t)(l) * CSR_STRIDE + 30016))
#define CSR_PKW(base, l)  ((int2*)((base) + (size_t)(l) * CSR_STRIDE + 30016))

// ---------------- CSR build ----------------
__global__ void count_all_kernel(const int* __restrict__ hg, const int* __restrict__ tg,
                                 int* __restrict__ degO, int* __restrict__ degI) {
  int tid = blockIdx.x * blockDim.x + threadIdx.x;
  if (tid >= 4 * EDGES) return;
  int l = tid / EDGES, j = tid - l * EDGES;
  const int* G = (l < 2) ? hg : tg;
  const int* src = G + (size_t)(l & 1) * 2 * EDGES;
  const int* dst = src + EDGES;
  atomicAdd(&degO[l * NN + src[j]], 1);
  atomicAdd(&degI[l * NN + dst[j]], 1);
}

__global__ __launch_bounds__(256) void scan1_kernel(const int* __restrict__ degI,
                                                    int* __restrict__ csrBase,
                                                    int* __restrict__ partials) {
  int l = blockIdx.x / NCH, ch = blockIdx.x - l * NCH;
  int tid = threadIdx.x;
  int i = ch * 256 + tid;
  __shared__ int buf[256];
  int v = (i < NN) ? degI[l * NN + i] : 0;
  buf[tid] = v;
  __syncthreads();
  for (int off = 1; off < 256; off <<= 1) {
    int t = (tid >= off) ? buf[tid - off] : 0;
    __syncthreads();
    buf[tid] += t;
    __syncthreads();
  }
  int* rp = CSR_RP(csrBase, l);
  if (i < NN) rp[i + 1] = buf[tid];
  if (tid == 255) partials[l * NCH + ch] = buf[255];
}

__global__ __launch_bounds__(128) void scan2_kernel(int* __restrict__ partials) {
  __shared__ int buf[128];
  int tid = threadIdx.x;
  for (int l = 0; l < 4; ++l) {
    int v = (tid < NCH) ? partials[l * NCH + tid] : 0;
    buf[tid] = v;
    __syncthreads();
    for (int off = 1; off < 128; off <<= 1) {
      int t = (tid >= off) ? buf[tid - off] : 0;
      __syncthreads();
      buf[tid] += t;
      __syncthreads();
    }
    if (tid < NCH) partials[l * NCH + tid] = buf[tid] - v;  // exclusive
    __syncthreads();
  }
}

__global__ __launch_bounds__(256) void fixup_kernel(int* __restrict__ csrBase,
                                                    int* __restrict__ cursor,
                                                    const int* __restrict__ partials) {
  int l = blockIdx.x / NCH, ch = blockIdx.x - l * NCH;
  int i = ch * 256 + threadIdx.x;
  int* rp = CSR_RP(csrBase, l);
  int off = partials[l * NCH + ch];
  if (i < NN) {
    int val = rp[i + 1] + off;
    rp[i + 1] = val;
    if (i + 1 < NN) cursor[l * NN + i + 1] = val;
  }
  if (i == 0) { rp[0] = 0; cursor[l * NN] = 0; }
}

__global__ void fill_all_kernel(const int* __restrict__ hg, const int* __restrict__ tg,
                                const int* __restrict__ degO, const int* __restrict__ degI,
                                int* __restrict__ cursor, int* __restrict__ csrBase) {
  int tid = blockIdx.x * blockDim.x + threadIdx.x;
  if (tid >= 4 * EDGES) return;
  int l = tid / EDGES, j = tid - l * EDGES;
  const int* G = (l < 2) ? hg : tg;
  const int* src = G + (size_t)(l & 1) * 2 * EDGES;
  const int* dst = src + EDGES;
  int s = src[j], d = dst[j];
  int doo = degO[l * NN + s]; if (doo < 1) doo = 1;
  int dii = degI[l * NN + d]; if (dii < 1) dii = 1;
  float nm = rsqrtf((float)doo) * rsqrtf((float)dii);
  int p = atomicAdd(&cursor[l * NN + d], 1);
  CSR_PKW(csrBase, l)[p] = make_int2(s, __float_as_int(nm));
}

// ---------------- block1 temporal GLU conv: x[B,N,6,1] -> X1h [N][64][8] fp16 ----------------
__global__ void glu1_kernel(const float* __restrict__ x, const float* __restrict__ w,
                            const float* __restrict__ b, __half* __restrict__ X1h) {
  int idx = blockIdx.x * blockDim.x + threadIdx.x;   // idx = n*64 + s, s = b*4 + t
  if (idx >= NN * 64) return;
  int n = idx >> 6, s = idx & 63;
  int bb = s >> 2, t = s & 3;
  const float* xb = x + ((long)bb * NN + n) * 6;
  float x0 = xb[t], x1 = xb[t + 1], x2 = xb[t + 2];
  float o[8];
#pragma unroll
  for (int c = 0; c < 8; ++c) {
    float p = w[c * 3 + 0] * x0 + w[c * 3 + 1] * x1 + w[c * 3 + 2] * x2 + b[c];
    float q = w[(c + 8) * 3 + 0] * x0 + w[(c + 8) * 3 + 1] * x1 + w[(c + 8) * 3 + 2] * x2 + b[c + 8];
    float al = (c == 0) ? x2 : 0.f;
    o[c] = (p + al) * sigmoidf_(q);
  }
  reinterpret_cast<float4*>(X1h)[idx] = pack8(o);
}

// ---------------- block1 pull (batched: all 4 lists gather the SHARED X1 buffer) ----------------
__global__ __launch_bounds__(256) void pull1_kernel(const int* __restrict__ csrBase,
                                                    const __half* __restrict__ Xh,
                                                    __half* __restrict__ T1hAll) {
  int gtid = blockIdx.x * 256 + threadIdx.x;
  int l = gtid / (NN * 64);
  int t = gtid - l * (NN * 64);
  int n = t >> 6, j = t & 63;
  const int* rp = CSR_RP(csrBase, l);
  const int2* pk = CSR_PK(csrBase, l);
  const float4* in4 = reinterpret_cast<const float4*>(Xh);
  float acc[8];
#pragma unroll
  for (int i = 0; i < 8; ++i) acc[i] = 0.f;
  int e = rp[n], end = rp[n + 1];
  for (; e + 4 <= end; e += 4) {
    int2 p0 = pk[e], p1 = pk[e + 1], p2 = pk[e + 2], p3 = pk[e + 3];
    float4 v0 = in4[(long)p0.x * 64 + j];
    float4 v1 = in4[(long)p1.x * 64 + j];
    float4 v2 = in4[(long)p2.x * 64 + j];
    float4 v3 = in4[(long)p3.x * 64 + j];
    float f[8];
    float n0 = __int_as_float(p0.y), n1 = __int_as_float(p1.y);
    float n2 = __int_as_float(p2.y), n3 = __int_as_float(p3.y);
    unpack8(v0, f);
#pragma unroll
    for (int i = 0; i < 8; ++i) acc[i] -= n0 * f[i];
    unpack8(v1, f);
#pragma unroll
    for (int i = 0; i < 8; ++i) acc[i] -= n1 * f[i];
    unpack8(v2, f);
#pragma unroll
    for (int i = 0; i < 8; ++i) acc[i] -= n2 * f[i];
    unpack8(v3, f);
#pragma unroll
    for (int i = 0; i < 8; ++i) acc[i] -= n3 * f[i];
  }
  for (; e < end; ++e) {
    int2 p = pk[e];
    float4 v = in4[(long)p.x * 64 + j];
    float nm = __int_as_float(p.y);
    float f[8];
    unpack8(v, f);
#pragma unroll
    for (int i = 0; i < 8; ++i) acc[i] -= nm * f[i];
  }
  reinterpret_cast<float4*>(T1hAll)[(size_t)l * (T1SLOT / 8) + t] = pack8(acc);
}

// ---------------- block1 fused Cheb combine (both graphs, both etypes; unroll-4 gathers) ----------
__global__ __launch_bounds__(256) void cheb1_kernel(const int* __restrict__ csrBase,
    const __half* __restrict__ Xh, const __half* __restrict__ T1hAll,
    const float* __restrict__ Whg, const float* __restrict__ bhg,
    const float* __restrict__ Wtg, const float* __restrict__ btg,
    __half* __restrict__ outH, __half* __restrict__ outT) {
  constexpr int C = 8, CC = 64;
  __shared__ float wx[CC], w1a[CC], w1b[CC], w2a[CC], w2b[CC], bs[C];
  int gtid = blockIdx.x * 256 + threadIdx.x;
  int g = gtid / (NN * 64);
  int tid = gtid - g * (NN * 64);
  const float* W = g ? Wtg : Whg;
  const float* bias = g ? btg : bhg;
  for (int i = threadIdx.x; i < CC; i += 256) {
    float w0A = W[i], w1A = W[CC + i], w2A = W[2 * CC + i];
    float w0B = W[3 * CC + i], w1B = W[4 * CC + i], w2B = W[5 * CC + i];
    wx[i] = w0A - w2A + w0B - w2B;
    w1a[i] = w1A; w1b[i] = w1B;
    w2a[i] = -2.f * w2A; w2b[i] = -2.f * w2B;
  }
  if (threadIdx.x < C) bs[threadIdx.x] = bias[threadIdx.x] + bias[C + threadIdx.x];
  __syncthreads();
  int n = tid >> 6, s = tid & 63;
  int l0 = 2 * g, l1 = 2 * g + 1;
  const int* rp0 = CSR_RP(csrBase, l0); const int2* pk0 = CSR_PK(csrBase, l0);
  const int* rp1 = CSR_RP(csrBase, l1); const int2* pk1 = CSR_PK(csrBase, l1);
  const float4* A4 = reinterpret_cast<const float4*>(T1hAll + (size_t)l0 * T1SLOT);
  const float4* B4 = reinterpret_cast<const float4*>(T1hAll + (size_t)l1 * T1SLOT);
  float acc0[C], acc1[C];
#pragma unroll
  for (int c = 0; c < C; ++c) { acc0[c] = 0.f; acc1[c] = 0.f; }
  {
    int e = rp0[n], end = rp0[n + 1];
    for (; e + 4 <= end; e += 4) {
      int2 p0 = pk0[e], p1 = pk0[e + 1], p2 = pk0[e + 2], p3 = pk0[e + 3];
      float4 v0 = A4[(long)p0.x * 64 + s];
      float4 v1 = A4[(long)p1.x * 64 + s];
      float4 v2 = A4[(long)p2.x * 64 + s];
      float4 v3 = A4[(long)p3.x * 64 + s];
      float n0 = __int_as_float(p0.y), n1 = __int_as_float(p1.y);
      float n2 = __int_as_float(p2.y), n3 = __int_as_float(p3.y);
      float f[8];
      unpack8(v0, f);
#pragma unroll
      for (int c = 0; c < C; ++c) acc0[c] += n0 * f[c];
      unpack8(v1, f);
#pragma unroll
      for (int c = 0; c < C; ++c) acc0[c] += n1 * f[c];
      unpack8(v2, f);
#pragma unroll
      for (int c = 0; c < C; ++c) acc0[c] += n2 * f[c];
      unpack8(v3, f);
#pragma unroll
      for (int c = 0; c < C; ++c) acc0[c] += n3 * f[c];
    }
    for (; e + 2 <= end; e += 2) {
      int2 p0 = pk0[e], p1 = pk0[e + 1];
      float4 v0 = A4[(long)p0.x * 64 + s];
      float4 v1 = A4[(long)p1.x * 64 + s];
      float n0 = __int_as_float(p0.y), n1 = __int_as_float(p1.y);
      float f0[8], f1[8];
      unpack8(v0, f0); unpack8(v1, f1);
#pragma unroll
      for (int c = 0; c < C; ++c) acc0[c] += n0 * f0[c] + n1 * f1[c];
    }
    for (; e < end; ++e) {
      int2 p = pk0[e];
      float4 v = A4[(long)p.x * 64 + s];
      float nm = __int_as_float(p.y);
      float f[8]; unpack8(v, f);
#pragma unroll
      for (int c = 0; c < C; ++c) acc0[c] += nm * f[c];
    }
  }
  {
    int e = rp1[n], end = rp1[n + 1];
    for (; e + 4 <= end; e += 4) {
      int2 p0 = pk1[e], p1 = pk1[e + 1], p2 = pk1[e + 2], p3 = pk1[e + 3];
      float4 v0 = B4[(long)p0.x * 64 + s];
      float4 v1 = B4[(long)p1.x * 64 + s];
      float4 v2 = B4[(long)p2.x * 64 + s];
      float4 v3 = B4[(long)p3.x * 64 + s];
      float n0 = __int_as_float(p0.y), n1 = __int_as_float(p1.y);
      float n2 = __int_as_float(p2.y), n3 = __int_as_float(p3.y);
      float f[8];
      unpack8(v0, f);
#pragma unroll
      for (int c = 0; c < C; ++c) acc1[c] += n0 * f[c];
      unpack8(v1, f);
#pragma unroll
      for (int c = 0; c < C; ++c) acc1[c] += n1 * f[c];
      unpack8(v2, f);
#pragma unroll
      for (int c = 0; c < C; ++c) acc1[c] += n2 * f[c];
      unpack8(v3, f);
#pragma unroll
      for (int c = 0; c < C; ++c) acc1[c] += n3 * f[c];
    }
    for (; e + 2 <= end; e += 2) {
      int2 p0 = pk1[e], p1 = pk1[e + 1];
      float4 v0 = B4[(long)p0.x * 64 + s];
      float4 v1 = B4[(long)p1.x * 64 + s];
      float n0 = __int_as_float(p0.y), n1 = __int_as_float(p1.y);
      float f0[8], f1[8];
      unpack8(v0, f0); unpack8(v1, f1);
#pragma unroll
      for (int c = 0; c < C; ++c) acc1[c] += n0 * f0[c] + n1 * f1[c];
    }
    for (; e < end; ++e) {
      int2 p = pk1[e];
      float4 v = B4[(long)p.x * 64 + s];
      float nm = __int_as_float(p.y);
      float f[8]; unpack8(v, f);
#pragma unroll
      for (int c = 0; c < C; ++c) acc1[c] += nm * f[c];
    }
  }
  float z[C];
#pragma unroll
  for (int d = 0; d < C; ++d) z[d] = bs[d];
  {
    float xv[8], av[8], bv[8];
    unpack8(reinterpret_cast<const float4*>(Xh)[tid], xv);
    unpack8(A4[tid], av);
    unpack8(B4[tid], bv);
#pragma unroll
    for (int c = 0; c < C; ++c) {
      float x0c = xv[c], tac = av[c], tbc = bv[c], a0 = acc0[c], a1 = acc1[c];
#pragma unroll
      for (int d = 0; d < C; ++d)
        z[d] += x0c * wx[c * C + d] + tac * w1a[c * C + d] + tbc * w1b[c * C + d] +
                a0 * w2a[c * C + d] + a1 * w2b[c * C + d];
    }
  }
  reinterpret_cast<float4*>(g ? outT : outH)[tid] = pack8(z);
}

// ---------------- block2 align(1x1)+GLU, rank-1-update form, hoisting-capped ----------------
__global__ __launch_bounds__(256) void glu2_kernel(const __half* __restrict__ H, const __half* __restrict__ Tt,
                                                   const float* __restrict__ w2, const float* __restrict__ b2,
                                                   const float* __restrict__ aw, const float* __restrict__ ab,
                                                   __half* __restrict__ X2nh) {
  __shared__ float wpq[48 * 24];   // 4.5 KB
  __shared__ float awl[16 * 12];   // 768 B
  __shared__ float bpq[22], bal[11];
  for (int i = threadIdx.x; i < 48 * 24; i += 256) {
    int k = i / 24, co = i - (i / 24) * 24;
    int tap = k >> 4, ci = k & 15;
    wpq[i] = (co < 22) ? w2[(co * 16 + ci) * 3 + tap] : 0.f;
  }
  for (int i = threadIdx.x; i < 16 * 12; i += 256) {
    int ci = i / 12, co = i - ci * 12;
    awl[i] = (co < 11) ? aw[co * 16 + ci] : 0.f;
  }
  if (threadIdx.x < 22) bpq[threadIdx.x] = b2[threadIdx.x];
  if (threadIdx.x < 11) bal[threadIdx.x] = ab[threadIdx.x];
  __syncthreads();
  int idx = blockIdx.x * 256 + threadIdx.x;   // idx = n*32 + s2, s2 = b*2 + t
  int n = idx >> 5, s = idx & 31;
  int bb = s >> 1, t = s & 1;
  long rbase = (long)n * 64 + bb * 4 + t;     // float4 row index (8 halfs per slice)
  const float4* H4 = reinterpret_cast<const float4*>(H) + rbase;
  const float4* T4 = reinterpret_cast<const float4*>(Tt) + rbase;
  float acc[24];        // [p0..p10 q0..q10 pad pad]
  float aac[12];
#pragma unroll
  for (int i = 0; i < 24; ++i) acc[i] = 0.f;
#pragma unroll
  for (int i = 0; i < 12; ++i) aac[i] = 0.f;
#pragma unroll 1
  for (int tap = 0; tap < 3; ++tap) {
    float hv8[8], tv8[8];
    unpack8(H4[tap], hv8);
    unpack8(T4[tap], tv8);
#pragma unroll 1
    for (int half_ = 0; half_ < 2; ++half_) {
#pragma unroll
      for (int c8 = 0; c8 < 8; ++c8) {
        float v = half_ ? tv8[c8] : hv8[c8];
        const float4* w4 = reinterpret_cast<const float4*>(&wpq[(tap * 16 + half_ * 8 + c8) * 24]);
#pragma unroll
        for (int j = 0; j < 6; ++j) {
          float4 wv = w4[j];
          acc[4 * j + 0] = fmaf(v, wv.x, acc[4 * j + 0]);
          acc[4 * j + 1] = fmaf(v, wv.y, acc[4 * j + 1]);
          acc[4 * j + 2] = fmaf(v, wv.z, acc[4 * j + 2]);
          acc[4 * j + 3] = fmaf(v, wv.w, acc[4 * j + 3]);
        }
        if (tap == 2) {
          const float4* a4 = reinterpret_cast<const float4*>(&awl[(half_ * 8 + c8) * 12]);
#pragma unroll
          for (int j = 0; j < 3; ++j) {
            float4 wv = a4[j];
            aac[4 * j + 0] = fmaf(v, wv.x, aac[4 * j + 0]);
            aac[4 * j + 1] = fmaf(v, wv.y, aac[4 * j + 1]);
            aac[4 * j + 2] = fmaf(v, wv.z, aac[4 * j + 2]);
            aac[4 * j + 3] = fmaf(v, wv.w, aac[4 * j + 3]);
          }
        }
      }
    }
  }
  float o[12];
  o[11] = 0.f;
#pragma unroll
  for (int co = 0; co < 11; ++co) {
    float p = acc[co] + bpq[co] + aac[co] + bal[co];
    float q = acc[co + 11] + bpq[co + 11];
    o[co] = p * sigmoidf_(q);
  }
  float2* o2 = reinterpret_cast<float2*>(X2nh) + (long)idx * 3;
  o2[0] = pack4(o);
  o2[1] = pack4(o + 4);
  o2[2] = pack4(o + 8);
}

// ---------------- block2 pull (batched: all 4 lists gather the SHARED X2nh buffer) ----------------
__global__ __launch_bounds__(256) void pull2_kernel(const int* __restrict__ csrBase,
                                                    const __half* __restrict__ Xh,
                                                    __half* __restrict__ T1hAll) {
  int gtid = blockIdx.x * 256 + threadIdx.x;
  int l = gtid / (NN * 96);
  int t = gtid - l * (NN * 96);
  int n = t / 96, j = t - n * 96;
  const int* rp = CSR_RP(csrBase, l);
  const int2* pk = CSR_PK(csrBase, l);
  const float2* in2 = reinterpret_cast<const float2*>(Xh);
  float acc[4];
#pragma unroll
  for (int i = 0; i < 4; ++i) acc[i] = 0.f;
  int e = rp[n], end = rp[n + 1];
  for (; e + 4 <= end; e += 4) {
    int2 p0 = pk[e], p1 = pk[e + 1], p2 = pk[e + 2], p3 = pk[e + 3];
    float2 v0 = in2[(long)p0.x * 96 + j];
    float2 v1 = in2[(long)p1.x * 96 + j];
    float2 v2 = in2[(long)p2.x * 96 + j];
    float2 v3 = in2[(long)p3.x * 96 + j];
    float f[4];
    float n0 = __int_as_float(p0.y), n1 = __int_as_float(p1.y);
    float n2 = __int_as_float(p2.y), n3 = __int_as_float(p3.y);
    unpack4(v0, f);
#pragma unroll
    for (int i = 0; i < 4; ++i) acc[i] -= n0 * f[i];
    unpack4(v1, f);
#pragma unroll
    for (int i = 0; i < 4; ++i) acc[i] -= n1 * f[i];
    unpack4(v2, f);
#pragma unroll
    for (int i = 0; i < 4; ++i) acc[i] -= n2 * f[i];
    unpack4(v3, f);
#pragma unroll
    for (int i = 0; i < 4; ++i) acc[i] -= n3 * f[i];
  }
  for (; e < end; ++e) {
    int2 p = pk[e];
    float2 v = in2[(long)p.x * 96 + j];
    float nm = __int_as_float(p.y);
    float f[4];
    unpack4(v, f);
#pragma unroll
    for (int i = 0; i < 4; ++i) acc[i] -= nm * f[i];
  }
  reinterpret_cast<float2*>(T1hAll)[(size_t)l * (T1SLOT / 4) + t] = pack4(acc);
}

// ---------------- block2 fused Cheb combine (both graphs, both etypes; unroll-4 gathers) ----------
__global__ __launch_bounds__(256) void cheb2_kernel(const int* __restrict__ csrBase,
    const __half* __restrict__ Xh, const __half* __restrict__ T1hAll,
    const float* __restrict__ Whg, const float* __restrict__ bhg,
    const float* __restrict__ Wtg, const float* __restrict__ btg,
    __half* __restrict__ outH, __half* __restrict__ outT) {
  constexpr int C = 11, CC = 121;
  __shared__ float wx[CC], w1a[CC], w1b[CC], w2a[CC], w2b[CC], bs[C];
  int gtid = blockIdx.x * 256 + threadIdx.x;
  int g = gtid / (NN * 32);
  int tid = gtid - g * (NN * 32);
  const float* W = g ? Wtg : Whg;
  const float* bias = g ? btg : bhg;
  for (int i = threadIdx.x; i < CC; i += 256) {
    float w0A = W[i], w1A = W[CC + i], w2A = W[2 * CC + i];
    float w0B = W[3 * CC + i], w1B = W[4 * CC + i], w2B = W[5 * CC + i];
    wx[i] = w0A - w2A + w0B - w2B;
    w1a[i] = w1A; w1b[i] = w1B;
    w2a[i] = -2.f * w2A; w2b[i] = -2.f * w2B;
  }
  if (threadIdx.x < C) bs[threadIdx.x] = bias[threadIdx.x] + bias[C + threadIdx.x];
  __syncthreads();
  int n = tid >> 5, s = tid & 31;
  int s3 = s * 3;
  int l0 = 2 * g, l1 = 2 * g + 1;
  const int* rp0 = CSR_RP(csrBase, l0); const int2* pk0 = CSR_PK(csrBase, l0);
  const int* rp1 = CSR_RP(csrBase, l1); const int2* pk1 = CSR_PK(csrBase, l1);
  const float2* A2v = reinterpret_cast<const float2*>(T1hAll + (size_t)l0 * T1SLOT);
  const float2* B2v = reinterpret_cast<const float2*>(T1hAll + (size_t)l1 * T1SLOT);
  float acc0[12], acc1[12];
#pragma unroll
  for (int c = 0; c < 12; ++c) { acc0[c] = 0.f; acc1[c] = 0.f; }
  {
    int e = rp0[n], end = rp0[n + 1];
    for (; e + 4 <= end; e += 4) {
      int2 p0 = pk0[e], p1 = pk0[e + 1], p2 = pk0[e + 2], p3 = pk0[e + 3];
      long r0 = (long)p0.x * 96 + s3, r1 = (long)p1.x * 96 + s3;
      long r2 = (long)p2.x * 96 + s3, r3 = (long)p3.x * 96 + s3;
      float2 a0 = A2v[r0], a1 = A2v[r0 + 1], a2 = A2v[r0 + 2];
      float2 b0 = A2v[r1], b1 = A2v[r1 + 1], b2 = A2v[r1 + 2];
      float2 c0 = A2v[r2], c1 = A2v[r2 + 1], c2 = A2v[r2 + 2];
      float2 d0 = A2v[r3], d1 = A2v[r3 + 1], d2 = A2v[r3 + 2];
      float n0 = __int_as_float(p0.y), n1 = __int_as_float(p1.y);
      float n2 = __int_as_float(p2.y), n3 = __int_as_float(p3.y);
      float f[4];
      unpack4(a0, f);
#pragma unroll
      for (int i = 0; i < 4; ++i) acc0[i] += n0 * f[i];
      unpack4(a1, f);
#pragma unroll
      for (int i = 0; i < 4; ++i) acc0[4 + i] += n0 * f[i];
      unpack4(a2, f);
#pragma unroll
      for (int i = 0; i < 4; ++i) acc0[8 + i] += n0 * f[i];
      unpack4(b0, f);
#pragma unroll
      for (int i = 0; i < 4; ++i) acc0[i] += n1 * f[i];
      unpack4(b1, f);
#pragma unroll
      for (int i = 0; i < 4; ++i) acc0[4 + i] += n1 * f[i];
      unpack4(b2, f);
#pragma unroll
      for (int i = 0; i < 4; ++i) acc0[8 + i] += n1 * f[i];
      unpack4(c0, f);
#pragma unroll
      for (int i = 0; i < 4; ++i) acc0[i] += n2 * f[i];
      unpack4(c1, f);
#pragma unroll
      for (int i = 0; i < 4; ++i) acc0[4 + i] += n2 * f[i];
      unpack4(c2, f);
#pragma unroll
      for (int i = 0; i < 4; ++i) acc0[8 + i] += n2 * f[i];
      unpack4(d0, f);
#pragma unroll
      for (int i = 0; i < 4; ++i) acc0[i] += n3 * f[i];
      unpack4(d1, f);
#pragma unroll
      for (int i = 0; i < 4; ++i) acc0[4 + i] += n3 * f[i];
      unpack4(d2, f);
#pragma unroll
      for (int i = 0; i < 4; ++i) acc0[8 + i] += n3 * f[i];
    }
    for (; e < end; ++e) {
      int2 p = pk0[e];
      long r = (long)p.x * 96 + s3;
      float2 a0 = A2v[r], a1 = A2v[r + 1], a2 = A2v[r + 2];
      float nm = __int_as_float(p.y);
      float f[4];
      unpack4(a0, f);
#pragma unroll
      for (int i = 0; i < 4; ++i) acc0[i] += nm * f[i];
      unpack4(a1, f);
#pragma unroll
      for (int i = 0; i < 4; ++i) acc0[4 + i] += nm * f[i];
      unpack4(a2, f);
#pragma unroll
      for (int i = 0; i < 4; ++i) acc0[8 + i] += nm * f[i];
    }
  }
  {
    int e = rp1[n], end = rp1[n + 1];
    for (; e + 4 <= end; e += 4) {
      int2 p0 = pk1[e], p1 = pk1[e + 1], p2 = pk1[e + 2], p3 = pk1[e + 3];
      long r0 = (long)p0.x * 96 + s3, r1 = (long)p1.x * 96 + s3;
      long r2 = (long)p2.x * 96 + s3, r3 = (long)p3.x * 96 + s3;
      float2 a0 = B2v[r0], a1 = B2v[r0 + 1], a2 = B2v[r0 + 2];
      float2 b0 = B2v[r1], b1 = B2v[r1 + 1], b2 = B2v[r1 + 2];
      float2 c0 = B2v[r2], c1 = B2v[r2 + 1], c2 = B2v[r2 + 2];
      float2 d0 = B2v[r3], d1 = B2v[r3 + 1], d2 = B2v[r3 + 2];
      float n0 = __int_as_float(p0.y), n1 = __int_as_float(p1.y);
      float n2 = __int_as_float(p2.y), n3 = __int_as_float(p3.y);
      float f[4];
      unpack4(a0, f);
#pragma unroll
      for (int i = 0; i < 4; ++i) acc1[i] += n0 * f[i];
      unpack4(a1, f);
#pragma unroll
      for (int i = 0; i < 4; ++i) acc1[4 + i] += n0 * f[i];
      unpack4(a2, f);
#pragma unroll
      for (int i = 0; i < 4; ++i) acc1[8 + i] += n0 * f[i];
      unpack4(b0, f);
#pragma unroll
      for (int i = 0; i < 4; ++i) acc1[i] += n1 * f[i];
      unpack4(b1, f);
#pragma unroll
      for (int i = 0; i < 4; ++i) acc1[4 + i] += n1 * f[i];
      unpack4(b2, f);
#pragma unroll
      for (int i = 0; i < 4; ++i) acc1[8 + i] += n1 * f[i];
      unpack4(c0, f);
#pragma unroll
      for (int i = 0; i < 4; ++i) acc1[i] += n2 * f[i];
      unpack4(c1, f);
#pragma unroll
      for (int i = 0; i < 4; ++i) acc1[4 + i] += n2 * f[i];
      unpack4(c2, f);
#pragma unroll
      for (int i = 0; i < 4; ++i) acc1[8 + i] += n2 * f[i];
      unpack4(d0, f);
#pragma unroll
      for (int i = 0; i < 4; ++i) acc1[i] += n3 * f[i];
      unpack4(d1, f);
#pragma unroll
      for (int i = 0; i < 4; ++i) acc1[4 + i] += n3 * f[i];
      unpack4(d2, f);
#pragma unroll
      for (int i = 0; i < 4; ++i) acc1[8 + i] += n3 * f[i];
    }
    for (; e < end; ++e) {
      int2 p = pk1[e];
      long r = (long)p.x * 96 + s3;
      float2 a0 = B2v[r], a1 = B2v[r + 1], a2 = B2v[r + 2];
      float nm = __int_as_float(p.y);
      float f[4];
      unpack4(a0, f);
#pragma unroll
      for (int i = 0; i < 4; ++i) acc1[i] += nm * f[i];
      unpack4(a1, f);
#pragma unroll
      for (int i = 0; i < 4; ++i) acc1[4 + i] += nm * f[i];
      unpack4(a2, f);
#pragma unroll
      for (int i = 0; i < 4; ++i) acc1[8 + i] += nm * f[i];
    }
  }
  float z[12];
#pragma unroll
  for (int d = 0; d < C; ++d) z[d] = bs[d];
  z[11] = 0.f;
  const float2* X2v = reinterpret_cast<const float2*>(Xh);
  long own = (long)tid * 3;
#pragma unroll
  for (int q = 0; q < 3; ++q) {
    float xv[4], av[4], bv[4];
    unpack4(X2v[own + q], xv);
    unpack4(A2v[own + q], av);
    unpack4(B2v[own + q], bv);
#pragma unroll
    for (int k = 0; k < 4; ++k) {
      int c = q * 4 + k;
      if (c == 11) continue;
      float x0c = xv[k], tac = av[k], tbc = bv[k], a0 = acc0[c], a1 = acc1[c];
#pragma unroll
      for (int d = 0; d < C; ++d)
        z[d] += x0c * wx[c * C + d] + tac * w1a[c * C + d] + tbc * w1b[c * C + d] +
                a0 * w2a[c * C + d] + a1 * w2b[c * C + d];
    }
  }
  float2* o2 = reinterpret_cast<float2*>(g ? outT : outH) + (long)tid * 3;
  o2[0] = pack4(z);
  o2[1] = pack4(z + 4);
  o2[2] = pack4(z + 8);
}

// ---------------- final: grid-stride; fp16->fp32 conversion ONCE during LDS staging ----------------
__global__ __launch_bounds__(256) void final_kernel(const __half* __restrict__ H2, const __half* __restrict__ T2b,
                                                    const float* __restrict__ W, const float* __restrict__ bias,
                                                    float* __restrict__ out) {
  __shared__ float zsr[64][48];   // 12 KB: z rows pre-converted to fp32
  int tid = threadIdx.x;
  int c = tid & 127, h = tid >> 7;
  float wp[48];
#pragma unroll
  for (int off = 0; off < 48; ++off) {
    int half_ = off / 24, r_ = off - half_ * 24;
    int t = r_ / 12, c_ = r_ - t * 12;
    wp[off] = (c_ == 11) ? 0.f : W[(2 * (c_ + half_ * 11) + t) * 128 + c];
  }
  float bh = bias[c];
  for (int tile = blockIdx.x; tile < 7500; tile += gridDim.x) {
    long r0 = (long)tile * 64;
    __syncthreads();
#pragma unroll
    for (int it = 0; it < 2; ++it) {
      int item = it * 256 + tid;          // 384 items = 64 rows x 6 float4 (8 halfs each)
      if (item < 384) {
        int row = item / 6, piece = item - row * 6;
        long r = r0 + row;
        int b = (int)(r / NN), n = (int)(r - (long)b * NN);
        const float4* srcb = reinterpret_cast<const float4*>(piece < 3 ? H2 : T2b);
        int f4i = (piece < 3) ? piece : piece - 3;
        float4 v = srcb[(long)n * 48 + b * 3 + f4i];
        float f[8];
        unpack8(v, f);
        float4* d = reinterpret_cast<float4*>(&zsr[row][(piece < 3 ? 0 : 24) + f4i * 8]);
        d[0] = make_float4(f[0], f[1], f[2], f[3]);
        d[1] = make_float4(f[4], f[5], f[6], f[7]);
      }
    }
    __syncthreads();
    int rbeg = h * 32;
#pragma unroll 2
    for (int row = rbeg; row < rbeg + 32; ++row) {
      const float4* zr4 = reinterpret_cast<const float4*>(&zsr[row][0]);
      float acc = bh;
#pragma unroll
      for (int q = 0; q < 12; ++q) {
        float4 zv = zr4[q];
        acc = fmaf(zv.x, wp[4 * q + 0], acc);
        acc = fmaf(zv.y, wp[4 * q + 1], acc);
        acc = fmaf(zv.z, wp[4 * q + 2], acc);
        acc = fmaf(zv.w, wp[4 * q + 3], acc);
      }
      out[(r0 + row) * 128 + c] = acc;
    }
  }
}

extern "C" void kernel_launch(void* const* d_in, const int* in_sizes, int n_in,
                              void* d_out, int out_size, void* d_ws, size_t ws_size,
                              hipStream_t stream) {
  const float* x    = (const float*)d_in[0];
  const int*   hg   = (const int*)d_in[1];
  const int*   tg   = (const int*)d_in[2];
  const float* t1w  = (const float*)d_in[3];
  const float* t1b  = (const float*)d_in[4];
  const float* h1W  = (const float*)d_in[5];
  const float* h1b  = (const float*)d_in[6];
  const float* g1W  = (const float*)d_in[7];
  const float* g1b  = (const float*)d_in[8];
  const float* a2w  = (const float*)d_in[9];
  const float* a2b  = (const float*)d_in[10];
  const float* t2w  = (const float*)d_in[11];
  const float* t2b  = (const float*)d_in[12];
  const float* h2W  = (const float*)d_in[13];
  const float* h2b  = (const float*)d_in[14];
  const float* g2W  = (const float*)d_in[15];
  const float* g2b  = (const float*)d_in[16];
  const float* outw = (const float*)d_in[17];
  const float* outb = (const float*)d_in[18];
  float* out = (float*)d_out;

  // workspace layout (round-6 structure)
  __half* T1h = (__half*)d_ws;                 // 4 slots x T1SLOT halfs (pull outputs)
  __half* Xh  = T1h + 4L * T1SLOT;             // X1 [N][64][8] -> X2n [N][32][12]
  __half* Cfh = Xh + T1SLOT;                   // block1 H out -> block2 H out
  __half* Dfh = Cfh + T1SLOT;                  // block1 T out -> block2 T out
  int* csrBase  = (int*)(Dfh + T1SLOT);        // 4 * CSR_STRIDE ints
  int* degO     = csrBase + 4 * CSR_STRIDE;    // 4*NN
  int* degI     = degO + 4 * NN;               // 4*NN
  int* cursor   = degI + 4 * NN;               // 4*NN
  int* partials = cursor + 4 * NN;             // 4*NCH

  // --- build CSR (sorted by dst) + norms for all 4 edge lists, batched ---
  hipMemsetAsync(degO, 0, 8 * NN * sizeof(int), stream);
  count_all_kernel<<<(4 * EDGES + 255) / 256, 256, 0, stream>>>(hg, tg, degO, degI);
  scan1_kernel<<<4 * NCH, 256, 0, stream>>>(degI, csrBase, partials);
  scan2_kernel<<<1, 128, 0, stream>>>(partials);
  fixup_kernel<<<4 * NCH, 256, 0, stream>>>(csrBase, cursor, partials);
  fill_all_kernel<<<(4 * EDGES + 255) / 256, 256, 0, stream>>>(hg, tg, degO, degI, cursor, csrBase);

  // --- block1 ---
  glu1_kernel<<<NN * 64 / 256, 256, 0, stream>>>(x, t1w, t1b, Xh);
  pull1_kernel<<<4 * NN * 64 / 256, 256, 0, stream>>>(csrBase, Xh, T1h);
  cheb1_kernel<<<2 * NN * 64 / 256, 256, 0, stream>>>(csrBase, Xh, T1h, h1W, h1b, g1W, g1b, Cfh, Dfh);

  // --- block2 ---
  glu2_kernel<<<NN * 32 / 256, 256, 0, stream>>>(Cfh, Dfh, t2w, t2b, a2w, a2b, Xh);
  pull2_kernel<<<4 * NN * 96 / 256, 256, 0, stream>>>(csrBase, Xh, T1h);
  cheb2_kernel<<<2 * NN * 32 / 256, 256, 0, stream>>>(csrBase, Xh, T1h, h2W, h2b, g2W, g2b, Cfh, Dfh);

  // --- final linear ---
  final_kernel<<<1024, 256, 0, stream>>>(Cfh, Dfh, outw, outb, out);
}